// Round 9
// baseline (224.899 us; speedup 1.0000x reference)
//
#include <hip/hip_runtime.h>
#include <hip/hip_bf16.h>
#include <cstdint>
#include <cstddef>

typedef __attribute__((ext_vector_type(8))) short bf16x8;
typedef __attribute__((ext_vector_type(4))) float f32x4;
typedef __attribute__((ext_vector_type(16))) float f32x16;

#define AS1 __attribute__((address_space(1)))
#define AS3 __attribute__((address_space(3)))

__device__ __forceinline__ void gload_lds16(const void* g, void* l) {
  __builtin_amdgcn_global_load_lds((const AS1 void*)g, (AS3 void*)l, 16, 0, 0);
}

__device__ __forceinline__ unsigned short f2bf(float x) {
  __hip_bfloat16 h = __float2bfloat16(x);
  return __builtin_bit_cast(unsigned short, h);
}
__device__ __forceinline__ float bf2f(unsigned short u) {
  return __builtin_bit_cast(float, (unsigned int)u << 16);
}

// ============ 1. f32 -> bf16 convert ============
__global__ __launch_bounds__(256) void k_cvt_bf16(const float* __restrict__ in,
                                                  unsigned short* __restrict__ out,
                                                  int n4) {
  int i = blockIdx.x * 256 + threadIdx.x;
  const int stride = gridDim.x * 256;
  for (; i < n4; i += stride) {
    float4 v = reinterpret_cast<const float4*>(in)[i];
    ushort4 o;
    o.x = f2bf(v.x); o.y = f2bf(v.y); o.z = f2bf(v.z); o.w = f2bf(v.w);
    reinterpret_cast<ushort4*>(out)[i] = o;
  }
}

// ============ 2. RoPE cos/sin tables [2048][64] ============
__global__ __launch_bounds__(256) void k_rope_tab(float* __restrict__ cosT,
                                                  float* __restrict__ sinT,
                                                  const int* __restrict__ hdim,
                                                  const int* __restrict__ wdim) {
  int idx = blockIdx.x * 256 + threadIdx.x;
  if (idx >= 2048 * 64) return;
  const int n = idx >> 6, j = idx & 63;
  const int H = *hdim, W = *wdim;
  const int w = n % W;
  const int rem = n / W;
  const int h = rem % H;
  const int t = rem / H;
  float pos, i2, d;
  if (j < 22)      { pos = (float)t; i2 = (float)(2 * j);        d = 44.f; }
  else if (j < 43) { pos = (float)h; i2 = (float)(2 * (j - 22)); d = 42.f; }
  else             { pos = (float)w; i2 = (float)(2 * (j - 43)); d = 42.f; }
  const float ang = pos * powf(10000.0f, -i2 / d);
  cosT[idx] = cosf(ang);
  sinT[idx] = sinf(ang);
}

// ============ 3a. 256x256 4-phase/K-tile GEMM, bf16 OUTPUT (QKV). XCD col-chunk.
__global__ __launch_bounds__(512, 2) void k_gemm256(const unsigned short* __restrict__ A,
                                                    const unsigned short* __restrict__ B,
                                                    const float* __restrict__ bias,
                                                    unsigned short* __restrict__ C,
                                                    int M, int N, int K) {
  __shared__ __align__(16) char lds[131072];
  const int tid = threadIdx.x;
  const int lane = tid & 63;
  const int wid = tid >> 6;
  const int wr = wid >> 2, wc = wid & 3;

  const int nbx = N >> 8;
  const int xcd = blockIdx.x & 7;
  const int t = blockIdx.x >> 3;
  const int cchunk = nbx >> 3;
  const int swz = (t & 7) * nbx + xcd * cchunk + (t >> 3);
  const int by = swz / nbx, bx = swz % nbx;
  const int row0 = by * 256, col0 = bx * 256;
  const int NT = K >> 6;

  auto stage_slot = [&](const unsigned short* src, int grow0, int kcol0, char* slot) {
#pragma unroll
    for (int r = 0; r < 2; ++r) {
      const int off = r * 8192 + tid * 16;
      const int pair = off >> 7;
      const int un = (off & 127) ^ ((pair & 7) << 4);
      const int grow = pair * 2 + (un >> 6);
      gload_lds16(src + (size_t)(grow0 + grow) * K + kcol0 + ((un & 63) >> 1),
                  slot + r * 8192 + wid * 1024);
    }
  };
  auto frag = [&](const char* slot, int r, int kb) -> bf16x8 {
    return *reinterpret_cast<const bf16x8*>(
        slot + (r >> 1) * 128 + ((((r & 1) << 6) + kb) ^ (((r >> 1) & 7) << 4)));
  };

  f32x4 acc[8][4];
#pragma unroll
  for (int i = 0; i < 8; ++i)
#pragma unroll
    for (int j = 0; j < 4; ++j) acc[i][j] = (f32x4){0.f, 0.f, 0.f, 0.f};

  stage_slot(A, row0, 0,  lds);
  stage_slot(B, col0, 0,  lds + 65536);
  stage_slot(A, row0, 32, lds + 16384);
  stage_slot(B, col0, 32, lds + 65536 + 16384);
  asm volatile("s_waitcnt vmcnt(4)" ::: "memory");
  __builtin_amdgcn_s_barrier();

  const int kb = (lane >> 4) << 4;
  for (int j = 0; j < NT; ++j) {
    const int b = j & 1, bp = b ^ 1;
    const char* A0 = lds + (2 * b + 0) * 16384;
    const char* A1 = lds + (2 * b + 1) * 16384;
    const char* B0 = lds + 65536 + (2 * b + 0) * 16384;
    const char* B1 = lds + 65536 + (2 * b + 1) * 16384;
    char* pA0 = lds + (2 * bp + 0) * 16384;
    char* pA1 = lds + (2 * bp + 1) * 16384;
    char* pB0 = lds + 65536 + (2 * bp + 0) * 16384;
    char* pB1 = lds + 65536 + (2 * bp + 1) * 16384;
    const bool pf = (j + 1 < NT);
    const int kn = (j + 1) * 64;
    bf16x8 af[8], bq[2];

#pragma unroll
    for (int rf = 0; rf < 8; ++rf) af[rf] = frag(A0, wr * 128 + rf * 16 + (lane & 15), kb);
#pragma unroll
    for (int cf = 0; cf < 2; ++cf) bq[cf] = frag(B0, wc * 64 + cf * 16 + (lane & 15), kb);
    if (pf) stage_slot(A, row0, kn, pA0);
    __builtin_amdgcn_s_barrier();
    __builtin_amdgcn_s_setprio(1);
#pragma unroll
    for (int rf = 0; rf < 8; ++rf)
#pragma unroll
      for (int cf = 0; cf < 2; ++cf)
        acc[rf][cf] = __builtin_amdgcn_mfma_f32_16x16x32_bf16(af[rf], bq[cf], acc[rf][cf], 0, 0, 0);
    __builtin_amdgcn_s_setprio(0);
    __builtin_amdgcn_s_barrier();

#pragma unroll
    for (int cf = 0; cf < 2; ++cf) bq[cf] = frag(B0, wc * 64 + (cf + 2) * 16 + (lane & 15), kb);
    if (pf) stage_slot(B, col0, kn, pB0);
    if (pf) asm volatile("s_waitcnt vmcnt(4)" ::: "memory");
    else    asm volatile("s_waitcnt vmcnt(0)" ::: "memory");
    __builtin_amdgcn_s_barrier();
    __builtin_amdgcn_s_setprio(1);
#pragma unroll
    for (int rf = 0; rf < 8; ++rf)
#pragma unroll
      for (int cf = 0; cf < 2; ++cf)
        acc[rf][cf + 2] = __builtin_amdgcn_mfma_f32_16x16x32_bf16(af[rf], bq[cf], acc[rf][cf + 2], 0, 0, 0);
    __builtin_amdgcn_s_setprio(0);
    __builtin_amdgcn_s_barrier();

#pragma unroll
    for (int rf = 0; rf < 8; ++rf) af[rf] = frag(A1, wr * 128 + rf * 16 + (lane & 15), kb);
#pragma unroll
    for (int cf = 0; cf < 2; ++cf) bq[cf] = frag(B1, wc * 64 + cf * 16 + (lane & 15), kb);
    if (pf) stage_slot(A, row0, kn + 32, pA1);
    __builtin_amdgcn_s_barrier();
    __builtin_amdgcn_s_setprio(1);
#pragma unroll
    for (int rf = 0; rf < 8; ++rf)
#pragma unroll
      for (int cf = 0; cf < 2; ++cf)
        acc[rf][cf] = __builtin_amdgcn_mfma_f32_16x16x32_bf16(af[rf], bq[cf], acc[rf][cf], 0, 0, 0);
    __builtin_amdgcn_s_setprio(0);
    __builtin_amdgcn_s_barrier();

#pragma unroll
    for (int cf = 0; cf < 2; ++cf) bq[cf] = frag(B1, wc * 64 + (cf + 2) * 16 + (lane & 15), kb);
    if (pf) stage_slot(B, col0, kn + 32, pB1);
    if (pf) asm volatile("s_waitcnt vmcnt(4)" ::: "memory");
    __builtin_amdgcn_s_barrier();
    __builtin_amdgcn_s_setprio(1);
#pragma unroll
    for (int rf = 0; rf < 8; ++rf)
#pragma unroll
      for (int cf = 0; cf < 2; ++cf)
        acc[rf][cf + 2] = __builtin_amdgcn_mfma_f32_16x16x32_bf16(af[rf], bq[cf], acc[rf][cf + 2], 0, 0, 0);
    __builtin_amdgcn_s_setprio(0);
    __builtin_amdgcn_s_barrier();
  }

#pragma unroll
  for (int fr = 0; fr < 8; ++fr)
#pragma unroll
    for (int fc = 0; fc < 4; ++fc) {
      const int col = col0 + wc * 64 + fc * 16 + (lane & 15);
      const float bv = bias[col];
#pragma unroll
      for (int jj = 0; jj < 4; ++jj) {
        const int row = row0 + wr * 128 + fr * 16 + (lane >> 4) * 4 + jj;
        C[(size_t)row * N + col] = f2bf(acc[fr][fc][jj] + bv);
      }
    }
}

// ============ 3b. 128x128 m97-structure GEMM, f32 out (proj) ====
__global__ __launch_bounds__(256) void k_gemm_bt(const unsigned short* __restrict__ A,
                                                 const unsigned short* __restrict__ B,
                                                 const float* __restrict__ bias,
                                                 float* __restrict__ C,
                                                 int M, int N, int K) {
  __shared__ __align__(16) unsigned short As[128 * 32];
  __shared__ __align__(16) unsigned short Bs[128 * 32];
  const int lane = threadIdx.x & 63;
  const int wid  = threadIdx.x >> 6;
  const int wr = wid >> 1, wc = wid & 1;
  const int rowA0 = blockIdx.y * 128;
  const int rowB0 = blockIdx.x * 128;

  f32x4 acc[4][4];
#pragma unroll
  for (int i = 0; i < 4; ++i)
#pragma unroll
    for (int j = 0; j < 4; ++j) acc[i][j] = (f32x4){0.f, 0.f, 0.f, 0.f};

  for (int kt = 0; kt < K; kt += 32) {
#pragma unroll
    for (int i = 0; i < 2; ++i) {
      const int c = i * 4 + wid;
      const int off = c * 1024 + lane * 16;
      const int row = off >> 6;
      const int col = (off & 63) >> 1;
      gload_lds16(A + (size_t)(rowA0 + row) * K + kt + col, (char*)As + c * 1024);
      gload_lds16(B + (size_t)(rowB0 + row) * K + kt + col, (char*)Bs + c * 1024);
    }
    __syncthreads();
    bf16x8 af[4], bfr[4];
#pragma unroll
    for (int mi = 0; mi < 4; ++mi)
      af[mi] = *reinterpret_cast<const bf16x8*>(
          &As[(wr * 64 + mi * 16 + (lane & 15)) * 32 + (lane >> 4) * 8]);
#pragma unroll
    for (int ni = 0; ni < 4; ++ni)
      bfr[ni] = *reinterpret_cast<const bf16x8*>(
          &Bs[(wc * 64 + ni * 16 + (lane & 15)) * 32 + (lane >> 4) * 8]);
#pragma unroll
    for (int mi = 0; mi < 4; ++mi)
#pragma unroll
      for (int ni = 0; ni < 4; ++ni)
        acc[mi][ni] = __builtin_amdgcn_mfma_f32_16x16x32_bf16(af[mi], bfr[ni], acc[mi][ni], 0, 0, 0);
    __syncthreads();
  }

#pragma unroll
  for (int mi = 0; mi < 4; ++mi)
#pragma unroll
    for (int ni = 0; ni < 4; ++ni) {
      const int col = rowB0 + wc * 64 + ni * 16 + (lane & 15);
      const float b = bias[col];
#pragma unroll
      for (int j = 0; j < 4; ++j) {
        const int row = rowA0 + wr * 64 + mi * 16 + (lane >> 4) * 4 + j;
        C[(size_t)row * N + col] = acc[mi][ni][j] + b;
      }
    }
}

// ============ 4a. q/k: RMSNorm + RoPE + (q: fold scale) from bf16 qkv -> bf16 [h][n][d]
__global__ __launch_bounds__(256) void k_qk_post(const unsigned short* __restrict__ qkv,
                                                 const float* __restrict__ qw,
                                                 const float* __restrict__ kw,
                                                 const float* __restrict__ cosT,
                                                 const float* __restrict__ sinT,
                                                 unsigned short* __restrict__ qo,
                                                 unsigned short* __restrict__ ko) {
  const int lane = threadIdx.x & 63;
  const int wid = threadIdx.x >> 6;
  const int pair = blockIdx.x * 4 + wid;  // (n,h)
  const int n = pair >> 4, h = pair & 15;
  const float c = cosT[n * 64 + lane];
  const float s = sinT[n * 64 + lane];
#pragma unroll
  for (int sq = 0; sq < 2; ++sq) {
    const unsigned short* src = qkv + (size_t)n * 6144 + sq * 2048 + h * 128;
    const unsigned int vp = reinterpret_cast<const unsigned int*>(src)[lane];
    const float vx = bf2f((unsigned short)(vp & 0xffff));
    const float vy = bf2f((unsigned short)(vp >> 16));
    float ss = vx * vx + vy * vy;
#pragma unroll
    for (int m = 1; m < 64; m <<= 1) ss += __shfl_xor(ss, m, 64);
    const float r = rsqrtf(ss * (1.0f / 128.0f) + 1e-6f);
    float2 wv = reinterpret_cast<const float2*>(sq == 0 ? qw : kw)[lane];
    const float xr = vx * r * wv.x;
    const float xi = vy * r * wv.y;
    float orr = xr * c - xi * s;
    float oi  = xr * s + xi * c;
    if (sq == 0) { orr *= 0.08838834764831845f; oi *= 0.08838834764831845f; }
    unsigned short* dst = (sq == 0 ? qo : ko) + ((size_t)h * 2048 + n) * 128 + 2 * lane;
    const unsigned int pk = (unsigned int)f2bf(orr) | ((unsigned int)f2bf(oi) << 16);
    *reinterpret_cast<unsigned int*>(dst) = pk;
  }
}

// ============ 4b. v: bf16 qkv -> vt2, MFMA-fragment-ordered (lane-direct) ====
__global__ __launch_bounds__(256) void k_v_tr(const unsigned short* __restrict__ qkv,
                                              unsigned short* __restrict__ vt2) {
  __shared__ __align__(16) unsigned short tile[64][136];
  const int h = blockIdx.y;
  const int n0 = blockIdx.x * 64;
  const int t = threadIdx.x;
  {
    const int row = t >> 2;
    const int c0 = (t & 3) * 32;
    const unsigned short* src = qkv + (size_t)(n0 + row) * 6144 + 4096 + h * 128 + c0;
#pragma unroll
    for (int j = 0; j < 32; j += 8)
      *reinterpret_cast<bf16x8*>(&tile[row][c0 + j]) =
          *reinterpret_cast<const bf16x8*>(src + j);
  }
  __syncthreads();
#pragma unroll
  for (int g4 = 0; g4 < 4; ++g4) {
    const int g = g4 * 256 + t;
    const int c = g >> 8;
    const int dblk = (g >> 6) & 3;
    const int p = g & 63;
    const int d = dblk * 32 + (p & 31);
    const int hi = p >> 5;
    bf16x8 o;
#pragma unroll
    for (int e = 0; e < 8; ++e) o[e] = (short)tile[c * 16 + hi * 8 + e][d];
    const size_t oidx = ((((size_t)h * 128 + (n0 >> 4) + c) * 4 + dblk) * 64 + p) * 8;
    *reinterpret_cast<bf16x8*>(vt2 + oidx) = o;
  }
}

// ============ 5. flash attention v6: T14 V-register prefetch at iteration top,
// ring-3 K staging, counted vmcnt, Ps stride 68 (2-way-free banks).
__global__ __launch_bounds__(256) void k_fattn(const unsigned short* __restrict__ q,
                                               const unsigned short* __restrict__ k,
                                               const unsigned short* __restrict__ vt2,
                                               unsigned short* __restrict__ Onorm,
                                               float* __restrict__ lseb) {
  __shared__ __align__(16) unsigned short Ks[3][64 * 128];   // 48 KB ring-3
  __shared__ __align__(16) unsigned short Ps[4][32][68];     // 136B rows, 2-way banks
  const int lane = threadIdx.x & 63;
  const int wid = threadIdx.x >> 6;
  const int hi2 = lane >> 5;
  const int ql = lane & 31;
  const int bid = blockIdx.x;
  const int h = bid & 15;
  const int qb = (bid >> 4) & 15;
  const int ksp = bid >> 8;              // 0..1
  const int q0 = qb * 128 + wid * 32;
  const int kbase = ksp * 1024;

  auto stageK = [&](int buf, int kt2) {
#pragma unroll
    for (int r = 0; r < 4; ++r) {
      const int off = r * 4096 + (wid * 64 + lane) * 16;
      const int row = off >> 8;
      const int colb = (off & 255) ^ ((row & 15) << 4);
      gload_lds16(k + ((size_t)h * 2048 + kbase + kt2 * 64 + row) * 128 + (colb >> 1),
                  (char*)Ks[buf] + r * 4096 + wid * 1024);
    }
  };

  bf16x8 qf[8];
  {
    const unsigned short* qp = q + ((size_t)h * 2048 + q0 + ql) * 128 + hi2 * 8;
#pragma unroll
    for (int c = 0; c < 8; ++c) qf[c] = *reinterpret_cast<const bf16x8*>(qp + c * 16);
  }
  f32x16 O[4];
#pragma unroll
  for (int i = 0; i < 4; ++i)
#pragma unroll
    for (int j = 0; j < 16; ++j) O[i][j] = 0.f;
  float m = -1e30f, l = 0.f;

  stageK(0, 0);
  stageK(1, 1);
  asm volatile("s_waitcnt vmcnt(4)" ::: "memory");
  __builtin_amdgcn_s_barrier();

  const int kswz = (lane & 15) << 4;
  for (int kt = 0; kt < 16; ++kt) {
    const int cur = kt % 3;

    // T14: issue ALL V loads for this tile first (they hide under QK^T+softmax),
    // then issue next-next K staging. PV's wait is then a counted vmcnt(4).
    const int cg0 = (kbase >> 4) + kt * 4;
    bf16x8 va[4][4];
#pragma unroll
    for (int dblk = 0; dblk < 4; ++dblk)
#pragma unroll
      for (int c2 = 0; c2 < 4; ++c2)
        va[dblk][c2] = *reinterpret_cast<const bf16x8*>(
            vt2 + ((((size_t)h * 128 + cg0 + c2) * 4 + dblk) * 64 + lane) * 8);
    if (kt + 2 < 16) stageK((kt + 2) % 3, kt + 2);

    f32x16 s0, s1;
#pragma unroll
    for (int j = 0; j < 16; ++j) { s0[j] = 0.f; s1[j] = 0.f; }
    __builtin_amdgcn_s_setprio(1);
#pragma unroll
    for (int c = 0; c < 8; ++c) {
      bf16x8 a0 = *reinterpret_cast<const bf16x8*>(
          (const char*)Ks[cur] + ql * 256 + ((c * 32 + hi2 * 16) ^ kswz));
      s0 = __builtin_amdgcn_mfma_f32_32x32x16_bf16(a0, qf[c], s0, 0, 0, 0);
    }
#pragma unroll
    for (int c = 0; c < 8; ++c) {
      bf16x8 a1 = *reinterpret_cast<const bf16x8*>(
          (const char*)Ks[cur] + (32 + ql) * 256 + ((c * 32 + hi2 * 16) ^ kswz));
      s1 = __builtin_amdgcn_mfma_f32_32x32x16_bf16(a1, qf[c], s1, 0, 0, 0);
    }
    __builtin_amdgcn_s_setprio(0);

    float mt = s0[0];
#pragma unroll
    for (int j = 1; j < 16; ++j) mt = fmaxf(mt, s0[j]);
#pragma unroll
    for (int j = 0; j < 16; ++j) mt = fmaxf(mt, s1[j]);
    mt = fmaxf(mt, __shfl_xor(mt, 32, 64));

    if (!__all(mt <= m + 8.0f)) {          // defer-max
      const float mn = fmaxf(m, mt);
      const float al = __expf(m - mn);
      m = mn;
      l *= al;
#pragma unroll
      for (int i = 0; i < 4; ++i)
#pragma unroll
        for (int j = 0; j < 16; ++j) O[i][j] *= al;
    }
    float rs = 0.f;
#pragma unroll
    for (int j = 0; j < 16; ++j) {
      s0[j] = __expf(s0[j] - m); rs += s0[j];
      s1[j] = __expf(s1[j] - m); rs += s1[j];
    }
    rs += __shfl_xor(rs, 32, 64);
    l += rs;

#pragma unroll
    for (int a = 0; a < 4; ++a) {
      uint2 w0, w1;
      w0.x = (unsigned)f2bf(s0[a * 4 + 0]) | ((unsigned)f2bf(s0[a * 4 + 1]) << 16);
      w0.y = (unsigned)f2bf(s0[a * 4 + 2]) | ((unsigned)f2bf(s0[a * 4 + 3]) << 16);
      w1.x = (unsigned)f2bf(s1[a * 4 + 0]) | ((unsigned)f2bf(s1[a * 4 + 1]) << 16);
      w1.y = (unsigned)f2bf(s1[a * 4 + 2]) | ((unsigned)f2bf(s1[a * 4 + 3]) << 16);
      *reinterpret_cast<uint2*>(&Ps[wid][ql][a * 8 + hi2 * 4]) = w0;
      *reinterpret_cast<uint2*>(&Ps[wid][ql][32 + a * 8 + hi2 * 4]) = w1;
    }
    bf16x8 pf[4];
#pragma unroll
    for (int c2 = 0; c2 < 4; ++c2) {
      uint2 u0 = *reinterpret_cast<const uint2*>(&Ps[wid][ql][c2 * 16 + hi2 * 8]);
      uint2 u1 = *reinterpret_cast<const uint2*>(&Ps[wid][ql][c2 * 16 + hi2 * 8 + 4]);
      union { uint4 u; bf16x8 v; } pu;
      pu.u.x = u0.x; pu.u.y = u0.y; pu.u.z = u1.x; pu.u.w = u1.y;
      pf[c2] = pu.v;
    }

    __builtin_amdgcn_s_setprio(1);
#pragma unroll
    for (int dblk = 0; dblk < 4; ++dblk)
#pragma unroll
      for (int c2 = 0; c2 < 4; ++c2)
        O[dblk] = __builtin_amdgcn_mfma_f32_32x32x16_bf16(va[dblk][c2], pf[c2], O[dblk], 0, 0, 0);
    __builtin_amdgcn_s_setprio(0);

    if (kt + 1 < 16) {
      asm volatile("s_waitcnt vmcnt(4)" ::: "memory");
      __builtin_amdgcn_s_barrier();
    }
  }

  const float rl = 1.0f / l;
  const int n = q0 + ql;
  unsigned short* ob = Onorm + (((size_t)(ksp * 16 + h) * 2048) + n) * 128;
#pragma unroll
  for (int dblk = 0; dblk < 4; ++dblk)
#pragma unroll
    for (int a = 0; a < 4; ++a) {
      uint2 w;
      w.x = (unsigned)f2bf(O[dblk][a * 4 + 0] * rl) | ((unsigned)f2bf(O[dblk][a * 4 + 1] * rl) << 16);
      w.y = (unsigned)f2bf(O[dblk][a * 4 + 2] * rl) | ((unsigned)f2bf(O[dblk][a * 4 + 3] * rl) << 16);
      *reinterpret_cast<uint2*>(ob + dblk * 32 + a * 8 + hi2 * 4) = w;
    }
  if (hi2 == 0)
    lseb[(size_t)(ksp * 16 + h) * 2048 + n] = m + logf(l);
}

// ============ 6. merge the two key-split partials ============
__global__ __launch_bounds__(256) void k_merge(const unsigned short* __restrict__ Onorm,
                                               const float* __restrict__ lseb,
                                               unsigned short* __restrict__ att) {
  const int idx = blockIdx.x * 256 + threadIdx.x;
  const int n = idx >> 8;
  const int r = idx & 255;
  const int h = r >> 4;
  const int d0 = (r & 15) * 8;
  const float l0 = lseb[(size_t)h * 2048 + n];
  const float l1 = lseb[(size_t)(16 + h) * 2048 + n];
  const float M = fmaxf(l0, l1);
  float w0 = __expf(l0 - M), w1 = __expf(l1 - M);
  const float inv = 1.0f / (w0 + w1);
  w0 *= inv; w1 *= inv;
  const bf16x8 o0 = *reinterpret_cast<const bf16x8*>(
      Onorm + ((size_t)h * 2048 + n) * 128 + d0);
  const bf16x8 o1 = *reinterpret_cast<const bf16x8*>(
      Onorm + ((size_t)(16 + h) * 2048 + n) * 128 + d0);
  bf16x8 o;
#pragma unroll
  for (int e = 0; e < 8; ++e)
    o[e] = (short)f2bf(bf2f((unsigned short)o0[e]) * w0 + bf2f((unsigned short)o1[e]) * w1);
  *reinterpret_cast<bf16x8*>(att + (size_t)n * 2048 + h * 128 + d0) = o;
}

extern "C" void kernel_launch(void* const* d_in, const int* in_sizes, int n_in,
                              void* d_out, int out_size, void* d_ws, size_t ws_size,
                              hipStream_t stream) {
  (void)in_sizes; (void)n_in; (void)out_size; (void)ws_size;
  const float* x      = (const float*)d_in[0];
  const float* qkv_w  = (const float*)d_in[1];
  const float* qkv_b  = (const float*)d_in[2];
  const float* proj_w = (const float*)d_in[3];
  const float* proj_b = (const float*)d_in[4];
  const float* q_nw   = (const float*)d_in[5];
  const float* k_nw   = (const float*)d_in[6];
  const int* h_dim    = (const int*)d_in[8];
  const int* w_dim    = (const int*)d_in[9];
  float* out = (float*)d_out;

  char* ws = (char*)d_ws;
  size_t off = 0;
  auto carve = [&](size_t bytes) -> void* {
    void* p = ws + off;
    off += (bytes + 255) & ~(size_t)255;
    return p;
  };
  unsigned short* x_bf   = (unsigned short*)carve(2048ull * 2048 * 2);
  unsigned short* w1_bf  = (unsigned short*)carve(6144ull * 2048 * 2);
  unsigned short* w2_bf  = (unsigned short*)carve(2048ull * 2048 * 2);
  unsigned short* qkvb   = (unsigned short*)carve(2048ull * 6144 * 2);
  unsigned short* q_bf   = (unsigned short*)carve(16ull * 2048 * 128 * 2);
  unsigned short* k_bf   = (unsigned short*)carve(16ull * 2048 * 128 * 2);
  unsigned short* vt2_bf = (unsigned short*)carve(16ull * 2048 * 128 * 2);
  unsigned short* att_bf = (unsigned short*)carve(2048ull * 2048 * 2);
  unsigned short* on_bf  = (unsigned short*)carve(2ull * 16 * 2048 * 128 * 2);
  float*          lseb   = (float*)carve(2ull * 16 * 2048 * 4);
  float*          cosT   = (float*)carve(2048ull * 64 * 4);
  float*          sinT   = (float*)carve(2048ull * 64 * 4);

  hipLaunchKernelGGL(k_cvt_bf16, dim3(2048), dim3(256), 0, stream, x, x_bf, 2048 * 2048 / 4);
  hipLaunchKernelGGL(k_cvt_bf16, dim3(2048), dim3(256), 0, stream, qkv_w, w1_bf, 6144 * 2048 / 4);
  hipLaunchKernelGGL(k_cvt_bf16, dim3(2048), dim3(256), 0, stream, proj_w, w2_bf, 2048 * 2048 / 4);
  hipLaunchKernelGGL(k_rope_tab, dim3(512), dim3(256), 0, stream, cosT, sinT, h_dim, w_dim);
  hipLaunchKernelGGL(k_gemm256, dim3(192), dim3(512), 0, stream,
                     x_bf, w1_bf, qkv_b, qkvb, 2048, 6144, 2048);
  hipLaunchKernelGGL(k_qk_post, dim3(8192), dim3(256), 0, stream,
                     qkvb, q_nw, k_nw, cosT, sinT, q_bf, k_bf);
  hipLaunchKernelGGL(k_v_tr, dim3(32, 16), dim3(256), 0, stream, qkvb, vt2_bf);
  hipLaunchKernelGGL(k_fattn, dim3(512), dim3(256), 0, stream,
                     q_bf, k_bf, vt2_bf, on_bf, lseb);
  hipLaunchKernelGGL(k_merge, dim3(2048), dim3(256), 0, stream, on_bf, lseb, att_bf);
  hipLaunchKernelGGL(k_gemm_bt, dim3(16, 16), dim3(256), 0, stream,
                     att_bf, w2_bf, proj_b, out, 2048, 2048, 2048);
}

// Round 10
// 207.549 us; speedup vs baseline: 1.0836x; 1.0836x over previous
//
#include <hip/hip_runtime.h>
#include <hip/hip_bf16.h>
#include <cstdint>
#include <cstddef>

typedef __attribute__((ext_vector_type(8))) short bf16x8;
typedef __attribute__((ext_vector_type(4))) float f32x4;
typedef __attribute__((ext_vector_type(16))) float f32x16;

#define AS1 __attribute__((address_space(1)))
#define AS3 __attribute__((address_space(3)))

__device__ __forceinline__ void gload_lds16(const void* g, void* l) {
  __builtin_amdgcn_global_load_lds((const AS1 void*)g, (AS3 void*)l, 16, 0, 0);
}

__device__ __forceinline__ unsigned short f2bf(float x) {
  __hip_bfloat16 h = __float2bfloat16(x);
  return __builtin_bit_cast(unsigned short, h);
}
__device__ __forceinline__ float bf2f(unsigned short u) {
  return __builtin_bit_cast(float, (unsigned int)u << 16);
}

// ============ 1. f32 -> bf16 convert ============
__global__ __launch_bounds__(256) void k_cvt_bf16(const float* __restrict__ in,
                                                  unsigned short* __restrict__ out,
                                                  int n4) {
  int i = blockIdx.x * 256 + threadIdx.x;
  const int stride = gridDim.x * 256;
  for (; i < n4; i += stride) {
    float4 v = reinterpret_cast<const float4*>(in)[i];
    ushort4 o;
    o.x = f2bf(v.x); o.y = f2bf(v.y); o.z = f2bf(v.z); o.w = f2bf(v.w);
    reinterpret_cast<ushort4*>(out)[i] = o;
  }
}

// ============ 2. RoPE cos/sin tables [2048][64] ============
__global__ __launch_bounds__(256) void k_rope_tab(float* __restrict__ cosT,
                                                  float* __restrict__ sinT,
                                                  const int* __restrict__ hdim,
                                                  const int* __restrict__ wdim) {
  int idx = blockIdx.x * 256 + threadIdx.x;
  if (idx >= 2048 * 64) return;
  const int n = idx >> 6, j = idx & 63;
  const int H = *hdim, W = *wdim;
  const int w = n % W;
  const int rem = n / W;
  const int h = rem % H;
  const int t = rem / H;
  float pos, i2, d;
  if (j < 22)      { pos = (float)t; i2 = (float)(2 * j);        d = 44.f; }
  else if (j < 43) { pos = (float)h; i2 = (float)(2 * (j - 22)); d = 42.f; }
  else             { pos = (float)w; i2 = (float)(2 * (j - 43)); d = 42.f; }
  const float ang = pos * powf(10000.0f, -i2 / d);
  cosT[idx] = cosf(ang);
  sinT[idx] = sinf(ang);
}

// ============ 3a. 256x256 4-phase/K-tile GEMM, bf16 OUTPUT (QKV). XCD col-chunk.
__global__ __launch_bounds__(512, 2) void k_gemm256(const unsigned short* __restrict__ A,
                                                    const unsigned short* __restrict__ B,
                                                    const float* __restrict__ bias,
                                                    unsigned short* __restrict__ C,
                                                    int M, int N, int K) {
  __shared__ __align__(16) char lds[131072];
  const int tid = threadIdx.x;
  const int lane = tid & 63;
  const int wid = tid >> 6;
  const int wr = wid >> 2, wc = wid & 3;

  const int nbx = N >> 8;
  const int xcd = blockIdx.x & 7;
  const int t = blockIdx.x >> 3;
  const int cchunk = nbx >> 3;
  const int swz = (t & 7) * nbx + xcd * cchunk + (t >> 3);
  const int by = swz / nbx, bx = swz % nbx;
  const int row0 = by * 256, col0 = bx * 256;
  const int NT = K >> 6;

  auto stage_slot = [&](const unsigned short* src, int grow0, int kcol0, char* slot) {
#pragma unroll
    for (int r = 0; r < 2; ++r) {
      const int off = r * 8192 + tid * 16;
      const int pair = off >> 7;
      const int un = (off & 127) ^ ((pair & 7) << 4);
      const int grow = pair * 2 + (un >> 6);
      gload_lds16(src + (size_t)(grow0 + grow) * K + kcol0 + ((un & 63) >> 1),
                  slot + r * 8192 + wid * 1024);
    }
  };
  auto frag = [&](const char* slot, int r, int kb) -> bf16x8 {
    return *reinterpret_cast<const bf16x8*>(
        slot + (r >> 1) * 128 + ((((r & 1) << 6) + kb) ^ (((r >> 1) & 7) << 4)));
  };

  f32x4 acc[8][4];
#pragma unroll
  for (int i = 0; i < 8; ++i)
#pragma unroll
    for (int j = 0; j < 4; ++j) acc[i][j] = (f32x4){0.f, 0.f, 0.f, 0.f};

  stage_slot(A, row0, 0,  lds);
  stage_slot(B, col0, 0,  lds + 65536);
  stage_slot(A, row0, 32, lds + 16384);
  stage_slot(B, col0, 32, lds + 65536 + 16384);
  asm volatile("s_waitcnt vmcnt(4)" ::: "memory");
  __builtin_amdgcn_s_barrier();

  const int kb = (lane >> 4) << 4;
  for (int j = 0; j < NT; ++j) {
    const int b = j & 1, bp = b ^ 1;
    const char* A0 = lds + (2 * b + 0) * 16384;
    const char* A1 = lds + (2 * b + 1) * 16384;
    const char* B0 = lds + 65536 + (2 * b + 0) * 16384;
    const char* B1 = lds + 65536 + (2 * b + 1) * 16384;
    char* pA0 = lds + (2 * bp + 0) * 16384;
    char* pA1 = lds + (2 * bp + 1) * 16384;
    char* pB0 = lds + 65536 + (2 * bp + 0) * 16384;
    char* pB1 = lds + 65536 + (2 * bp + 1) * 16384;
    const bool pf = (j + 1 < NT);
    const int kn = (j + 1) * 64;
    bf16x8 af[8], bq[2];

#pragma unroll
    for (int rf = 0; rf < 8; ++rf) af[rf] = frag(A0, wr * 128 + rf * 16 + (lane & 15), kb);
#pragma unroll
    for (int cf = 0; cf < 2; ++cf) bq[cf] = frag(B0, wc * 64 + cf * 16 + (lane & 15), kb);
    if (pf) stage_slot(A, row0, kn, pA0);
    __builtin_amdgcn_s_barrier();
    __builtin_amdgcn_s_setprio(1);
#pragma unroll
    for (int rf = 0; rf < 8; ++rf)
#pragma unroll
      for (int cf = 0; cf < 2; ++cf)
        acc[rf][cf] = __builtin_amdgcn_mfma_f32_16x16x32_bf16(af[rf], bq[cf], acc[rf][cf], 0, 0, 0);
    __builtin_amdgcn_s_setprio(0);
    __builtin_amdgcn_s_barrier();

#pragma unroll
    for (int cf = 0; cf < 2; ++cf) bq[cf] = frag(B0, wc * 64 + (cf + 2) * 16 + (lane & 15), kb);
    if (pf) stage_slot(B, col0, kn, pB0);
    if (pf) asm volatile("s_waitcnt vmcnt(4)" ::: "memory");
    else    asm volatile("s_waitcnt vmcnt(0)" ::: "memory");
    __builtin_amdgcn_s_barrier();
    __builtin_amdgcn_s_setprio(1);
#pragma unroll
    for (int rf = 0; rf < 8; ++rf)
#pragma unroll
      for (int cf = 0; cf < 2; ++cf)
        acc[rf][cf + 2] = __builtin_amdgcn_mfma_f32_16x16x32_bf16(af[rf], bq[cf], acc[rf][cf + 2], 0, 0, 0);
    __builtin_amdgcn_s_setprio(0);
    __builtin_amdgcn_s_barrier();

#pragma unroll
    for (int rf = 0; rf < 8; ++rf) af[rf] = frag(A1, wr * 128 + rf * 16 + (lane & 15), kb);
#pragma unroll
    for (int cf = 0; cf < 2; ++cf) bq[cf] = frag(B1, wc * 64 + cf * 16 + (lane & 15), kb);
    if (pf) stage_slot(A, row0, kn + 32, pA1);
    __builtin_amdgcn_s_barrier();
    __builtin_amdgcn_s_setprio(1);
#pragma unroll
    for (int rf = 0; rf < 8; ++rf)
#pragma unroll
      for (int cf = 0; cf < 2; ++cf)
        acc[rf][cf] = __builtin_amdgcn_mfma_f32_16x16x32_bf16(af[rf], bq[cf], acc[rf][cf], 0, 0, 0);
    __builtin_amdgcn_s_setprio(0);
    __builtin_amdgcn_s_barrier();

#pragma unroll
    for (int cf = 0; cf < 2; ++cf) bq[cf] = frag(B1, wc * 64 + (cf + 2) * 16 + (lane & 15), kb);
    if (pf) stage_slot(B, col0, kn + 32, pB1);
    if (pf) asm volatile("s_waitcnt vmcnt(4)" ::: "memory");
    __builtin_amdgcn_s_barrier();
    __builtin_amdgcn_s_setprio(1);
#pragma unroll
    for (int rf = 0; rf < 8; ++rf)
#pragma unroll
      for (int cf = 0; cf < 2; ++cf)
        acc[rf][cf + 2] = __builtin_amdgcn_mfma_f32_16x16x32_bf16(af[rf], bq[cf], acc[rf][cf + 2], 0, 0, 0);
    __builtin_amdgcn_s_setprio(0);
    __builtin_amdgcn_s_barrier();
  }

#pragma unroll
  for (int fr = 0; fr < 8; ++fr)
#pragma unroll
    for (int fc = 0; fc < 4; ++fc) {
      const int col = col0 + wc * 64 + fc * 16 + (lane & 15);
      const float bv = bias[col];
#pragma unroll
      for (int jj = 0; jj < 4; ++jj) {
        const int row = row0 + wr * 128 + fr * 16 + (lane >> 4) * 4 + jj;
        C[(size_t)row * N + col] = f2bf(acc[fr][fc][jj] + bv);
      }
    }
}

// ============ 3b. 128x128 m97-structure GEMM with split-K (proj).
// blockIdx.z selects K-half; partials (no bias) to Cp[z][M][N] f32.
__global__ __launch_bounds__(256) void k_gemm_bt_sk(const unsigned short* __restrict__ A,
                                                    const unsigned short* __restrict__ B,
                                                    float* __restrict__ Cp,
                                                    int M, int N, int K, int KS) {
  __shared__ __align__(16) unsigned short As[128 * 32];
  __shared__ __align__(16) unsigned short Bs[128 * 32];
  const int lane = threadIdx.x & 63;
  const int wid  = threadIdx.x >> 6;
  const int wr = wid >> 1, wc = wid & 1;
  const int rowA0 = blockIdx.y * 128;
  const int rowB0 = blockIdx.x * 128;
  const int k0 = blockIdx.z * KS;

  f32x4 acc[4][4];
#pragma unroll
  for (int i = 0; i < 4; ++i)
#pragma unroll
    for (int j = 0; j < 4; ++j) acc[i][j] = (f32x4){0.f, 0.f, 0.f, 0.f};

  for (int kt = k0; kt < k0 + KS; kt += 32) {
#pragma unroll
    for (int i = 0; i < 2; ++i) {
      const int c = i * 4 + wid;
      const int off = c * 1024 + lane * 16;
      const int row = off >> 6;
      const int col = (off & 63) >> 1;
      gload_lds16(A + (size_t)(rowA0 + row) * K + kt + col, (char*)As + c * 1024);
      gload_lds16(B + (size_t)(rowB0 + row) * K + kt + col, (char*)Bs + c * 1024);
    }
    __syncthreads();
    bf16x8 af[4], bfr[4];
#pragma unroll
    for (int mi = 0; mi < 4; ++mi)
      af[mi] = *reinterpret_cast<const bf16x8*>(
          &As[(wr * 64 + mi * 16 + (lane & 15)) * 32 + (lane >> 4) * 8]);
#pragma unroll
    for (int ni = 0; ni < 4; ++ni)
      bfr[ni] = *reinterpret_cast<const bf16x8*>(
          &Bs[(wc * 64 + ni * 16 + (lane & 15)) * 32 + (lane >> 4) * 8]);
#pragma unroll
    for (int mi = 0; mi < 4; ++mi)
#pragma unroll
      for (int ni = 0; ni < 4; ++ni)
        acc[mi][ni] = __builtin_amdgcn_mfma_f32_16x16x32_bf16(af[mi], bfr[ni], acc[mi][ni], 0, 0, 0);
    __syncthreads();
  }

  float* Cz = Cp + (size_t)blockIdx.z * M * N;
#pragma unroll
  for (int mi = 0; mi < 4; ++mi)
#pragma unroll
    for (int ni = 0; ni < 4; ++ni) {
      const int col = rowB0 + wc * 64 + ni * 16 + (lane & 15);
#pragma unroll
      for (int j = 0; j < 4; ++j) {
        const int row = rowA0 + wr * 64 + mi * 16 + (lane >> 4) * 4 + j;
        Cz[(size_t)row * N + col] = acc[mi][ni][j];
      }
    }
}

// ============ 3c. sum split-K partials + bias -> f32 out ============
__global__ __launch_bounds__(256) void k_addbias(const float* __restrict__ Cp,
                                                 const float* __restrict__ bias,
                                                 float* __restrict__ out) {
  const int i = blockIdx.x * 256 + threadIdx.x;   // float4 index over 2048^2
  const float4 a = reinterpret_cast<const float4*>(Cp)[i];
  const float4 b = reinterpret_cast<const float4*>(Cp + 2048ull * 2048)[i];
  const float4 bv = reinterpret_cast<const float4*>(bias)[i & 511];
  float4 o;
  o.x = a.x + b.x + bv.x; o.y = a.y + b.y + bv.y;
  o.z = a.z + b.z + bv.z; o.w = a.w + b.w + bv.w;
  reinterpret_cast<float4*>(out)[i] = o;
}

// ============ 4a. q/k: RMSNorm + RoPE + (q: fold scale) from bf16 qkv -> bf16 [h][n][d]
__global__ __launch_bounds__(256) void k_qk_post(const unsigned short* __restrict__ qkv,
                                                 const float* __restrict__ qw,
                                                 const float* __restrict__ kw,
                                                 const float* __restrict__ cosT,
                                                 const float* __restrict__ sinT,
                                                 unsigned short* __restrict__ qo,
                                                 unsigned short* __restrict__ ko) {
  const int lane = threadIdx.x & 63;
  const int wid = threadIdx.x >> 6;
  const int pair = blockIdx.x * 4 + wid;  // (n,h)
  const int n = pair >> 4, h = pair & 15;
  const float c = cosT[n * 64 + lane];
  const float s = sinT[n * 64 + lane];
#pragma unroll
  for (int sq = 0; sq < 2; ++sq) {
    const unsigned short* src = qkv + (size_t)n * 6144 + sq * 2048 + h * 128;
    const unsigned int vp = reinterpret_cast<const unsigned int*>(src)[lane];
    const float vx = bf2f((unsigned short)(vp & 0xffff));
    const float vy = bf2f((unsigned short)(vp >> 16));
    float ss = vx * vx + vy * vy;
#pragma unroll
    for (int m = 1; m < 64; m <<= 1) ss += __shfl_xor(ss, m, 64);
    const float r = rsqrtf(ss * (1.0f / 128.0f) + 1e-6f);
    float2 wv = reinterpret_cast<const float2*>(sq == 0 ? qw : kw)[lane];
    const float xr = vx * r * wv.x;
    const float xi = vy * r * wv.y;
    float orr = xr * c - xi * s;
    float oi  = xr * s + xi * c;
    if (sq == 0) { orr *= 0.08838834764831845f; oi *= 0.08838834764831845f; }
    unsigned short* dst = (sq == 0 ? qo : ko) + ((size_t)h * 2048 + n) * 128 + 2 * lane;
    const unsigned int pk = (unsigned int)f2bf(orr) | ((unsigned int)f2bf(oi) << 16);
    *reinterpret_cast<unsigned int*>(dst) = pk;
  }
}

// ============ 4b. v: bf16 qkv -> vt2, MFMA-fragment-ordered (lane-direct) ====
__global__ __launch_bounds__(256) void k_v_tr(const unsigned short* __restrict__ qkv,
                                              unsigned short* __restrict__ vt2) {
  __shared__ __align__(16) unsigned short tile[64][136];
  const int h = blockIdx.y;
  const int n0 = blockIdx.x * 64;
  const int t = threadIdx.x;
  {
    const int row = t >> 2;
    const int c0 = (t & 3) * 32;
    const unsigned short* src = qkv + (size_t)(n0 + row) * 6144 + 4096 + h * 128 + c0;
#pragma unroll
    for (int j = 0; j < 32; j += 8)
      *reinterpret_cast<bf16x8*>(&tile[row][c0 + j]) =
          *reinterpret_cast<const bf16x8*>(src + j);
  }
  __syncthreads();
#pragma unroll
  for (int g4 = 0; g4 < 4; ++g4) {
    const int g = g4 * 256 + t;
    const int c = g >> 8;
    const int dblk = (g >> 6) & 3;
    const int p = g & 63;
    const int d = dblk * 32 + (p & 31);
    const int hi = p >> 5;
    bf16x8 o;
#pragma unroll
    for (int e = 0; e < 8; ++e) o[e] = (short)tile[c * 16 + hi * 8 + e][d];
    const size_t oidx = ((((size_t)h * 128 + (n0 >> 4) + c) * 4 + dblk) * 64 + p) * 8;
    *reinterpret_cast<bf16x8*>(vt2 + oidx) = o;
  }
}

// ============ 5. flash attention (R8 structure + Ps[68]): 32 q/wave, 32x32x16,
// V direct from L2 (inline loads), ring-3 K staging, counted vmcnt.
__global__ __launch_bounds__(256) void k_fattn(const unsigned short* __restrict__ q,
                                               const unsigned short* __restrict__ k,
                                               const unsigned short* __restrict__ vt2,
                                               unsigned short* __restrict__ Onorm,
                                               float* __restrict__ lseb) {
  __shared__ __align__(16) unsigned short Ks[3][64 * 128];   // 48 KB ring-3
  __shared__ __align__(16) unsigned short Ps[4][32][68];     // 136B rows, 2-way banks
  const int lane = threadIdx.x & 63;
  const int wid = threadIdx.x >> 6;
  const int hi2 = lane >> 5;
  const int ql = lane & 31;
  const int bid = blockIdx.x;
  const int h = bid & 15;
  const int qb = (bid >> 4) & 15;
  const int ksp = bid >> 8;              // 0..1
  const int q0 = qb * 128 + wid * 32;
  const int kbase = ksp * 1024;

  auto stageK = [&](int buf, int kt2) {
#pragma unroll
    for (int r = 0; r < 4; ++r) {
      const int off = r * 4096 + (wid * 64 + lane) * 16;
      const int row = off >> 8;
      const int colb = (off & 255) ^ ((row & 15) << 4);
      gload_lds16(k + ((size_t)h * 2048 + kbase + kt2 * 64 + row) * 128 + (colb >> 1),
                  (char*)Ks[buf] + r * 4096 + wid * 1024);
    }
  };

  bf16x8 qf[8];
  {
    const unsigned short* qp = q + ((size_t)h * 2048 + q0 + ql) * 128 + hi2 * 8;
#pragma unroll
    for (int c = 0; c < 8; ++c) qf[c] = *reinterpret_cast<const bf16x8*>(qp + c * 16);
  }
  f32x16 O[4];
#pragma unroll
  for (int i = 0; i < 4; ++i)
#pragma unroll
    for (int j = 0; j < 16; ++j) O[i][j] = 0.f;
  float m = -1e30f, l = 0.f;

  stageK(0, 0);
  stageK(1, 1);
  asm volatile("s_waitcnt vmcnt(4)" ::: "memory");
  __builtin_amdgcn_s_barrier();

  const int kswz = (lane & 15) << 4;
  for (int kt = 0; kt < 16; ++kt) {
    const int cur = kt % 3;

    f32x16 s0, s1;
#pragma unroll
    for (int j = 0; j < 16; ++j) { s0[j] = 0.f; s1[j] = 0.f; }
    __builtin_amdgcn_s_setprio(1);
#pragma unroll
    for (int c = 0; c < 8; ++c) {
      bf16x8 a0 = *reinterpret_cast<const bf16x8*>(
          (const char*)Ks[cur] + ql * 256 + ((c * 32 + hi2 * 16) ^ kswz));
      s0 = __builtin_amdgcn_mfma_f32_32x32x16_bf16(a0, qf[c], s0, 0, 0, 0);
    }
#pragma unroll
    for (int c = 0; c < 8; ++c) {
      bf16x8 a1 = *reinterpret_cast<const bf16x8*>(
          (const char*)Ks[cur] + (32 + ql) * 256 + ((c * 32 + hi2 * 16) ^ kswz));
      s1 = __builtin_amdgcn_mfma_f32_32x32x16_bf16(a1, qf[c], s1, 0, 0, 0);
    }
    __builtin_amdgcn_s_setprio(0);

    float mt = s0[0];
#pragma unroll
    for (int j = 1; j < 16; ++j) mt = fmaxf(mt, s0[j]);
#pragma unroll
    for (int j = 0; j < 16; ++j) mt = fmaxf(mt, s1[j]);
    mt = fmaxf(mt, __shfl_xor(mt, 32, 64));

    if (!__all(mt <= m + 8.0f)) {          // defer-max
      const float mn = fmaxf(m, mt);
      const float al = __expf(m - mn);
      m = mn;
      l *= al;
#pragma unroll
      for (int i = 0; i < 4; ++i)
#pragma unroll
        for (int j = 0; j < 16; ++j) O[i][j] *= al;
    }
    float rs = 0.f;
#pragma unroll
    for (int j = 0; j < 16; ++j) {
      s0[j] = __expf(s0[j] - m); rs += s0[j];
      s1[j] = __expf(s1[j] - m); rs += s1[j];
    }
    rs += __shfl_xor(rs, 32, 64);
    l += rs;

#pragma unroll
    for (int a = 0; a < 4; ++a) {
      uint2 w0, w1;
      w0.x = (unsigned)f2bf(s0[a * 4 + 0]) | ((unsigned)f2bf(s0[a * 4 + 1]) << 16);
      w0.y = (unsigned)f2bf(s0[a * 4 + 2]) | ((unsigned)f2bf(s0[a * 4 + 3]) << 16);
      w1.x = (unsigned)f2bf(s1[a * 4 + 0]) | ((unsigned)f2bf(s1[a * 4 + 1]) << 16);
      w1.y = (unsigned)f2bf(s1[a * 4 + 2]) | ((unsigned)f2bf(s1[a * 4 + 3]) << 16);
      *reinterpret_cast<uint2*>(&Ps[wid][ql][a * 8 + hi2 * 4]) = w0;
      *reinterpret_cast<uint2*>(&Ps[wid][ql][32 + a * 8 + hi2 * 4]) = w1;
    }
    bf16x8 pf[4];
#pragma unroll
    for (int c2 = 0; c2 < 4; ++c2) {
      uint2 u0 = *reinterpret_cast<const uint2*>(&Ps[wid][ql][c2 * 16 + hi2 * 8]);
      uint2 u1 = *reinterpret_cast<const uint2*>(&Ps[wid][ql][c2 * 16 + hi2 * 8 + 4]);
      union { uint4 u; bf16x8 v; } pu;
      pu.u.x = u0.x; pu.u.y = u0.y; pu.u.z = u1.x; pu.u.w = u1.y;
      pf[c2] = pu.v;
    }

    const int cg0 = (kbase >> 4) + kt * 4;
    __builtin_amdgcn_s_setprio(1);
#pragma unroll
    for (int dblk = 0; dblk < 4; ++dblk) {
#pragma unroll
      for (int c2 = 0; c2 < 4; ++c2) {
        bf16x8 va = *reinterpret_cast<const bf16x8*>(
            vt2 + ((((size_t)h * 128 + cg0 + c2) * 4 + dblk) * 64 + lane) * 8);
        O[dblk] = __builtin_amdgcn_mfma_f32_32x32x16_bf16(va, pf[c2], O[dblk], 0, 0, 0);
      }
    }
    __builtin_amdgcn_s_setprio(0);

    if (kt + 2 < 16) stageK((kt + 2) % 3, kt + 2);
    if (kt + 1 < 16) {
      asm volatile("s_waitcnt vmcnt(4)" ::: "memory");
      __builtin_amdgcn_s_barrier();
    }
  }

  const float rl = 1.0f / l;
  const int n = q0 + ql;
  unsigned short* ob = Onorm + (((size_t)(ksp * 16 + h) * 2048) + n) * 128;
#pragma unroll
  for (int dblk = 0; dblk < 4; ++dblk)
#pragma unroll
    for (int a = 0; a < 4; ++a) {
      uint2 w;
      w.x = (unsigned)f2bf(O[dblk][a * 4 + 0] * rl) | ((unsigned)f2bf(O[dblk][a * 4 + 1] * rl) << 16);
      w.y = (unsigned)f2bf(O[dblk][a * 4 + 2] * rl) | ((unsigned)f2bf(O[dblk][a * 4 + 3] * rl) << 16);
      *reinterpret_cast<uint2*>(ob + dblk * 32 + a * 8 + hi2 * 4) = w;
    }
  if (hi2 == 0)
    lseb[(size_t)(ksp * 16 + h) * 2048 + n] = m + logf(l);
}

// ============ 6. merge the two key-split partials ============
__global__ __launch_bounds__(256) void k_merge(const unsigned short* __restrict__ Onorm,
                                               const float* __restrict__ lseb,
                                               unsigned short* __restrict__ att) {
  const int idx = blockIdx.x * 256 + threadIdx.x;
  const int n = idx >> 8;
  const int r = idx & 255;
  const int h = r >> 4;
  const int d0 = (r & 15) * 8;
  const float l0 = lseb[(size_t)h * 2048 + n];
  const float l1 = lseb[(size_t)(16 + h) * 2048 + n];
  const float M = fmaxf(l0, l1);
  float w0 = __expf(l0 - M), w1 = __expf(l1 - M);
  const float inv = 1.0f / (w0 + w1);
  w0 *= inv; w1 *= inv;
  const bf16x8 o0 = *reinterpret_cast<const bf16x8*>(
      Onorm + ((size_t)h * 2048 + n) * 128 + d0);
  const bf16x8 o1 = *reinterpret_cast<const bf16x8*>(
      Onorm + ((size_t)(16 + h) * 2048 + n) * 128 + d0);
  bf16x8 o;
#pragma unroll
  for (int e = 0; e < 8; ++e)
    o[e] = (short)f2bf(bf2f((unsigned short)o0[e]) * w0 + bf2f((unsigned short)o1[e]) * w1);
  *reinterpret_cast<bf16x8*>(att + (size_t)n * 2048 + h * 128 + d0) = o;
}

extern "C" void kernel_launch(void* const* d_in, const int* in_sizes, int n_in,
                              void* d_out, int out_size, void* d_ws, size_t ws_size,
                              hipStream_t stream) {
  (void)in_sizes; (void)n_in; (void)out_size; (void)ws_size;
  const float* x      = (const float*)d_in[0];
  const float* qkv_w  = (const float*)d_in[1];
  const float* qkv_b  = (const float*)d_in[2];
  const float* proj_w = (const float*)d_in[3];
  const float* proj_b = (const float*)d_in[4];
  const float* q_nw   = (const float*)d_in[5];
  const float* k_nw   = (const float*)d_in[6];
  const int* h_dim    = (const int*)d_in[8];
  const int* w_dim    = (const int*)d_in[9];
  float* out = (float*)d_out;

  char* ws = (char*)d_ws;
  size_t off = 0;
  auto carve = [&](size_t bytes) -> void* {
    void* p = ws + off;
    off += (bytes + 255) & ~(size_t)255;
    return p;
  };
  unsigned short* x_bf   = (unsigned short*)carve(2048ull * 2048 * 2);
  unsigned short* w1_bf  = (unsigned short*)carve(6144ull * 2048 * 2);
  unsigned short* w2_bf  = (unsigned short*)carve(2048ull * 2048 * 2);
  unsigned short* qkvb   = (unsigned short*)carve(2048ull * 6144 * 2);
  unsigned short* q_bf   = (unsigned short*)carve(16ull * 2048 * 128 * 2);
  unsigned short* k_bf   = (unsigned short*)carve(16ull * 2048 * 128 * 2);
  unsigned short* vt2_bf = (unsigned short*)carve(16ull * 2048 * 128 * 2);
  unsigned short* att_bf = (unsigned short*)carve(2048ull * 2048 * 2);
  unsigned short* on_bf  = (unsigned short*)carve(2ull * 16 * 2048 * 128 * 2);
  float*          lseb   = (float*)carve(2ull * 16 * 2048 * 4);
  float*          projp  = (float*)carve(2ull * 2048 * 2048 * 4);
  float*          cosT   = (float*)carve(2048ull * 64 * 4);
  float*          sinT   = (float*)carve(2048ull * 64 * 4);

  hipLaunchKernelGGL(k_cvt_bf16, dim3(2048), dim3(256), 0, stream, x, x_bf, 2048 * 2048 / 4);
  hipLaunchKernelGGL(k_cvt_bf16, dim3(2048), dim3(256), 0, stream, qkv_w, w1_bf, 6144 * 2048 / 4);
  hipLaunchKernelGGL(k_cvt_bf16, dim3(2048), dim3(256), 0, stream, proj_w, w2_bf, 2048 * 2048 / 4);
  hipLaunchKernelGGL(k_rope_tab, dim3(512), dim3(256), 0, stream, cosT, sinT, h_dim, w_dim);
  hipLaunchKernelGGL(k_gemm256, dim3(192), dim3(512), 0, stream,
                     x_bf, w1_bf, qkv_b, qkvb, 2048, 6144, 2048);
  hipLaunchKernelGGL(k_qk_post, dim3(8192), dim3(256), 0, stream,
                     qkvb, q_nw, k_nw, cosT, sinT, q_bf, k_bf);
  hipLaunchKernelGGL(k_v_tr, dim3(32, 16), dim3(256), 0, stream, qkvb, vt2_bf);
  hipLaunchKernelGGL(k_fattn, dim3(512), dim3(256), 0, stream,
                     q_bf, k_bf, vt2_bf, on_bf, lseb);
  hipLaunchKernelGGL(k_merge, dim3(2048), dim3(256), 0, stream, on_bf, lseb, att_bf);
  hipLaunchKernelGGL(k_gemm_bt_sk, dim3(16, 16, 2), dim3(256), 0, stream,
                     att_bf, w2_bf, projp, 2048, 2048, 2048, 1024);
  hipLaunchKernelGGL(k_addbias, dim3(4096), dim3(256), 0, stream, projp, proj_b, out);
}

// Round 11
// 204.194 us; speedup vs baseline: 1.1014x; 1.0164x over previous
//
#include <hip/hip_runtime.h>
#include <hip/hip_bf16.h>
#include <cstdint>
#include <cstddef>

typedef __attribute__((ext_vector_type(8))) short bf16x8;
typedef __attribute__((ext_vector_type(4))) float f32x4;
typedef __attribute__((ext_vector_type(16))) float f32x16;

#define AS1 __attribute__((address_space(1)))
#define AS3 __attribute__((address_space(3)))

__device__ __forceinline__ void gload_lds16(const void* g, void* l) {
  __builtin_amdgcn_global_load_lds((const AS1 void*)g, (AS3 void*)l, 16, 0, 0);
}

__device__ __forceinline__ unsigned short f2bf(float x) {
  __hip_bfloat16 h = __float2bfloat16(x);
  return __builtin_bit_cast(unsigned short, h);
}
__device__ __forceinline__ float bf2f(unsigned short u) {
  return __builtin_bit_cast(float, (unsigned int)u << 16);
}

// ============ 1. f32 -> bf16 convert ============
__global__ __launch_bounds__(256) void k_cvt_bf16(const float* __restrict__ in,
                                                  unsigned short* __restrict__ out,
                                                  int n4) {
  int i = blockIdx.x * 256 + threadIdx.x;
  const int stride = gridDim.x * 256;
  for (; i < n4; i += stride) {
    float4 v = reinterpret_cast<const float4*>(in)[i];
    ushort4 o;
    o.x = f2bf(v.x); o.y = f2bf(v.y); o.z = f2bf(v.z); o.w = f2bf(v.w);
    reinterpret_cast<ushort4*>(out)[i] = o;
  }
}

// ============ 2. RoPE cos/sin tables [2048][64] ============
__global__ __launch_bounds__(256) void k_rope_tab(float* __restrict__ cosT,
                                                  float* __restrict__ sinT,
                                                  const int* __restrict__ hdim,
                                                  const int* __restrict__ wdim) {
  int idx = blockIdx.x * 256 + threadIdx.x;
  if (idx >= 2048 * 64) return;
  const int n = idx >> 6, j = idx & 63;
  const int H = *hdim, W = *wdim;
  const int w = n % W;
  const int rem = n / W;
  const int h = rem % H;
  const int t = rem / H;
  float pos, i2, d;
  if (j < 22)      { pos = (float)t; i2 = (float)(2 * j);        d = 44.f; }
  else if (j < 43) { pos = (float)h; i2 = (float)(2 * (j - 22)); d = 42.f; }
  else             { pos = (float)w; i2 = (float)(2 * (j - 43)); d = 42.f; }
  const float ang = pos * powf(10000.0f, -i2 / d);
  cosT[idx] = cosf(ang);
  sinT[idx] = sinf(ang);
}

// ============ 3a. QKV GEMM: 128x192 tile, BK=64, 2-phase/K-tile counted-vmcnt,
// 4 waves, ring-2 LDS 80KB -> 2 blocks/CU, grid 512 (full machine). bf16 out.
// Layout per slot: row-pair packed, phys(r,kb)= (r>>1)*128 + (((r&1)*64+kb)^(((r>>1)&7)<<4))
__global__ __launch_bounds__(256, 2) void k_gemmQKV(const unsigned short* __restrict__ A,
                                                    const unsigned short* __restrict__ B,
                                                    const float* __restrict__ bias,
                                                    unsigned short* __restrict__ C,
                                                    int M, int N, int K) {
  __shared__ __align__(16) char lds[81920];   // 2 bufs x (A0 8K | A1 8K | B0 12K | B1 12K)
  const int tid = threadIdx.x;
  const int lane = tid & 63;
  const int wid = tid >> 6;
  const int wr = wid >> 1, wc = wid & 1;

  const int xcd = blockIdx.x & 7;
  const int t = blockIdx.x >> 3;              // 0..63 per XCD
  const int bx = xcd * 4 + (t & 3);           // 4 col-tiles per XCD (768 cols, 3MB B in L2)
  const int by = t >> 2;
  const int row0 = by * 128, col0 = bx * 192;
  const int NT = K >> 6;

  // A-slot: [128][32bf16] = 8KB, 2 rounds; B-slot: [192][32] = 12KB, 3 rounds.
  auto stageA = [&](int grow0, int kcol0, char* slot) {
#pragma unroll
    for (int r = 0; r < 2; ++r) {
      const int off = r * 4096 + tid * 16;
      const int pair = off >> 7;
      const int un = (off & 127) ^ ((pair & 7) << 4);
      const int grow = pair * 2 + (un >> 6);
      gload_lds16(A + (size_t)(grow0 + grow) * K + kcol0 + ((un & 63) >> 1),
                  slot + r * 4096 + wid * 1024);
    }
  };
  auto stageB = [&](int grow0, int kcol0, char* slot) {
#pragma unroll
    for (int r = 0; r < 3; ++r) {
      const int off = r * 4096 + tid * 16;
      const int pair = off >> 7;
      const int un = (off & 127) ^ ((pair & 7) << 4);
      const int grow = pair * 2 + (un >> 6);
      gload_lds16(B + (size_t)(grow0 + grow) * K + kcol0 + ((un & 63) >> 1),
                  slot + r * 4096 + wid * 1024);
    }
  };
  auto frag = [&](const char* slot, int r, int kb) -> bf16x8 {
    return *reinterpret_cast<const bf16x8*>(
        slot + (r >> 1) * 128 + ((((r & 1) << 6) + kb) ^ (((r >> 1) & 7) << 4)));
  };

  f32x4 acc[4][6];
#pragma unroll
  for (int i = 0; i < 4; ++i)
#pragma unroll
    for (int j = 0; j < 6; ++j) acc[i][j] = (f32x4){0.f, 0.f, 0.f, 0.f};

  // Prologue: tile 0 -> buf 0, order A0,B0,A1,B1 (10 loads); vmcnt(5) confirms A0,B0.
  stageA(row0, 0,  lds);
  stageB(col0, 0,  lds + 16384);
  stageA(row0, 32, lds + 8192);
  stageB(col0, 32, lds + 28672);
  asm volatile("s_waitcnt vmcnt(5)" ::: "memory");
  __builtin_amdgcn_s_barrier();

  const int kb = (lane >> 4) << 4;
  for (int j = 0; j < NT; ++j) {
    const int b = j & 1, bp = b ^ 1;
    const char* base = lds + b * 40960;
    char* pbase = lds + bp * 40960;
    const bool pf = (j + 1 < NT);
    const int kn = (j + 1) * 64;
    bf16x8 af[4], bq[6];

    // ---- ph1: ks0 (A0,B0); stage next tile's A0',B0' ----
#pragma unroll
    for (int fr = 0; fr < 4; ++fr) af[fr] = frag(base, wr * 64 + fr * 16 + (lane & 15), kb);
#pragma unroll
    for (int fc = 0; fc < 6; ++fc) bq[fc] = frag(base + 16384, wc * 96 + fc * 16 + (lane & 15), kb);
    if (pf) { stageA(row0, kn, pbase); stageB(col0, kn, pbase + 16384); }
    // confirm this tile's A1,B1 (leaves A0',B0' in flight)
    if (pf) asm volatile("s_waitcnt vmcnt(5)" ::: "memory");
    else    asm volatile("s_waitcnt vmcnt(0)" ::: "memory");
    __builtin_amdgcn_s_barrier();
    __builtin_amdgcn_s_setprio(1);
#pragma unroll
    for (int fr = 0; fr < 4; ++fr)
#pragma unroll
      for (int fc = 0; fc < 6; ++fc)
        acc[fr][fc] = __builtin_amdgcn_mfma_f32_16x16x32_bf16(af[fr], bq[fc], acc[fr][fc], 0, 0, 0);
    __builtin_amdgcn_s_setprio(0);
    __builtin_amdgcn_s_barrier();

    // ---- ph2: ks1 (A1,B1); stage next tile's A1',B1' ----
#pragma unroll
    for (int fr = 0; fr < 4; ++fr) af[fr] = frag(base + 8192, wr * 64 + fr * 16 + (lane & 15), kb);
#pragma unroll
    for (int fc = 0; fc < 6; ++fc) bq[fc] = frag(base + 28672, wc * 96 + fc * 16 + (lane & 15), kb);
    if (pf) { stageA(row0, kn + 32, pbase + 8192); stageB(col0, kn + 32, pbase + 28672); }
    // confirm next tile's A0',B0' (leaves A1',B1' in flight)
    if (pf) asm volatile("s_waitcnt vmcnt(5)" ::: "memory");
    __builtin_amdgcn_s_barrier();
    __builtin_amdgcn_s_setprio(1);
#pragma unroll
    for (int fr = 0; fr < 4; ++fr)
#pragma unroll
      for (int fc = 0; fc < 6; ++fc)
        acc[fr][fc] = __builtin_amdgcn_mfma_f32_16x16x32_bf16(af[fr], bq[fc], acc[fr][fc], 0, 0, 0);
    __builtin_amdgcn_s_setprio(0);
    __builtin_amdgcn_s_barrier();
  }

#pragma unroll
  for (int fr = 0; fr < 4; ++fr)
#pragma unroll
    for (int fc = 0; fc < 6; ++fc) {
      const int col = col0 + wc * 96 + fc * 16 + (lane & 15);
      const float bv = bias[col];
#pragma unroll
      for (int jj = 0; jj < 4; ++jj) {
        const int row = row0 + wr * 64 + fr * 16 + (lane >> 4) * 4 + jj;
        C[(size_t)row * N + col] = f2bf(acc[fr][fc][jj] + bv);
      }
    }
}

// ============ 3b. 128x128 m97-structure GEMM with split-K (proj) ====
__global__ __launch_bounds__(256) void k_gemm_bt_sk(const unsigned short* __restrict__ A,
                                                    const unsigned short* __restrict__ B,
                                                    float* __restrict__ Cp,
                                                    int M, int N, int K, int KS) {
  __shared__ __align__(16) unsigned short As[128 * 32];
  __shared__ __align__(16) unsigned short Bs[128 * 32];
  const int lane = threadIdx.x & 63;
  const int wid  = threadIdx.x >> 6;
  const int wr = wid >> 1, wc = wid & 1;
  const int rowA0 = blockIdx.y * 128;
  const int rowB0 = blockIdx.x * 128;
  const int k0 = blockIdx.z * KS;

  f32x4 acc[4][4];
#pragma unroll
  for (int i = 0; i < 4; ++i)
#pragma unroll
    for (int j = 0; j < 4; ++j) acc[i][j] = (f32x4){0.f, 0.f, 0.f, 0.f};

  for (int kt = k0; kt < k0 + KS; kt += 32) {
#pragma unroll
    for (int i = 0; i < 2; ++i) {
      const int c = i * 4 + wid;
      const int off = c * 1024 + lane * 16;
      const int row = off >> 6;
      const int col = (off & 63) >> 1;
      gload_lds16(A + (size_t)(rowA0 + row) * K + kt + col, (char*)As + c * 1024);
      gload_lds16(B + (size_t)(rowB0 + row) * K + kt + col, (char*)Bs + c * 1024);
    }
    __syncthreads();
    bf16x8 af[4], bfr[4];
#pragma unroll
    for (int mi = 0; mi < 4; ++mi)
      af[mi] = *reinterpret_cast<const bf16x8*>(
          &As[(wr * 64 + mi * 16 + (lane & 15)) * 32 + (lane >> 4) * 8]);
#pragma unroll
    for (int ni = 0; ni < 4; ++ni)
      bfr[ni] = *reinterpret_cast<const bf16x8*>(
          &Bs[(wc * 64 + ni * 16 + (lane & 15)) * 32 + (lane >> 4) * 8]);
#pragma unroll
    for (int mi = 0; mi < 4; ++mi)
#pragma unroll
      for (int ni = 0; ni < 4; ++ni)
        acc[mi][ni] = __builtin_amdgcn_mfma_f32_16x16x32_bf16(af[mi], bfr[ni], acc[mi][ni], 0, 0, 0);
    __syncthreads();
  }

  float* Cz = Cp + (size_t)blockIdx.z * M * N;
#pragma unroll
  for (int mi = 0; mi < 4; ++mi)
#pragma unroll
    for (int ni = 0; ni < 4; ++ni) {
      const int col = rowB0 + wc * 64 + ni * 16 + (lane & 15);
#pragma unroll
      for (int j = 0; j < 4; ++j) {
        const int row = rowA0 + wr * 64 + mi * 16 + (lane >> 4) * 4 + j;
        Cz[(size_t)row * N + col] = acc[mi][ni][j];
      }
    }
}

// ============ 3c. sum split-K partials + bias -> f32 out ============
__global__ __launch_bounds__(256) void k_addbias(const float* __restrict__ Cp,
                                                 const float* __restrict__ bias,
                                                 float* __restrict__ out) {
  const int i = blockIdx.x * 256 + threadIdx.x;   // float4 index over 2048^2
  const float4 a = reinterpret_cast<const float4*>(Cp)[i];
  const float4 b = reinterpret_cast<const float4*>(Cp + 2048ull * 2048)[i];
  const float4 bv = reinterpret_cast<const float4*>(bias)[i & 511];
  float4 o;
  o.x = a.x + b.x + bv.x; o.y = a.y + b.y + bv.y;
  o.z = a.z + b.z + bv.z; o.w = a.w + b.w + bv.w;
  reinterpret_cast<float4*>(out)[i] = o;
}

// ============ 4a. q/k: RMSNorm + RoPE + (q: fold scale) from bf16 qkv -> bf16 [h][n][d]
__global__ __launch_bounds__(256) void k_qk_post(const unsigned short* __restrict__ qkv,
                                                 const float* __restrict__ qw,
                                                 const float* __restrict__ kw,
                                                 const float* __restrict__ cosT,
                                                 const float* __restrict__ sinT,
                                                 unsigned short* __restrict__ qo,
                                                 unsigned short* __restrict__ ko) {
  const int lane = threadIdx.x & 63;
  const int wid = threadIdx.x >> 6;
  const int pair = blockIdx.x * 4 + wid;  // (n,h)
  const int n = pair >> 4, h = pair & 15;
  const float c = cosT[n * 64 + lane];
  const float s = sinT[n * 64 + lane];
#pragma unroll
  for (int sq = 0; sq < 2; ++sq) {
    const unsigned short* src = qkv + (size_t)n * 6144 + sq * 2048 + h * 128;
    const unsigned int vp = reinterpret_cast<const unsigned int*>(src)[lane];
    const float vx = bf2f((unsigned short)(vp & 0xffff));
    const float vy = bf2f((unsigned short)(vp >> 16));
    float ss = vx * vx + vy * vy;
#pragma unroll
    for (int m = 1; m < 64; m <<= 1) ss += __shfl_xor(ss, m, 64);
    const float r = rsqrtf(ss * (1.0f / 128.0f) + 1e-6f);
    float2 wv = reinterpret_cast<const float2*>(sq == 0 ? qw : kw)[lane];
    const float xr = vx * r * wv.x;
    const float xi = vy * r * wv.y;
    float orr = xr * c - xi * s;
    float oi  = xr * s + xi * c;
    if (sq == 0) { orr *= 0.08838834764831845f; oi *= 0.08838834764831845f; }
    unsigned short* dst = (sq == 0 ? qo : ko) + ((size_t)h * 2048 + n) * 128 + 2 * lane;
    const unsigned int pk = (unsigned int)f2bf(orr) | ((unsigned int)f2bf(oi) << 16);
    *reinterpret_cast<unsigned int*>(dst) = pk;
  }
}

// ============ 4b. v: bf16 qkv -> vt2, MFMA-fragment-ordered (lane-direct) ====
__global__ __launch_bounds__(256) void k_v_tr(const unsigned short* __restrict__ qkv,
                                              unsigned short* __restrict__ vt2) {
  __shared__ __align__(16) unsigned short tile[64][136];
  const int h = blockIdx.y;
  const int n0 = blockIdx.x * 64;
  const int t = threadIdx.x;
  {
    const int row = t >> 2;
    const int c0 = (t & 3) * 32;
    const unsigned short* src = qkv + (size_t)(n0 + row) * 6144 + 4096 + h * 128 + c0;
#pragma unroll
    for (int j = 0; j < 32; j += 8)
      *reinterpret_cast<bf16x8*>(&tile[row][c0 + j]) =
          *reinterpret_cast<const bf16x8*>(src + j);
  }
  __syncthreads();
#pragma unroll
  for (int g4 = 0; g4 < 4; ++g4) {
    const int g = g4 * 256 + t;
    const int c = g >> 8;
    const int dblk = (g >> 6) & 3;
    const int p = g & 63;
    const int d = dblk * 32 + (p & 31);
    const int hi = p >> 5;
    bf16x8 o;
#pragma unroll
    for (int e = 0; e < 8; ++e) o[e] = (short)tile[c * 16 + hi * 8 + e][d];
    const size_t oidx = ((((size_t)h * 128 + (n0 >> 4) + c) * 4 + dblk) * 64 + p) * 8;
    *reinterpret_cast<bf16x8*>(vt2 + oidx) = o;
  }
}

// ============ 5. flash attention: 32 q/wave, 32x32x16, V direct from L2,
// ring-3 K staging, counted vmcnt, Ps[68] (2-way-free banks).
__global__ __launch_bounds__(256) void k_fattn(const unsigned short* __restrict__ q,
                                               const unsigned short* __restrict__ k,
                                               const unsigned short* __restrict__ vt2,
                                               unsigned short* __restrict__ Onorm,
                                               float* __restrict__ lseb) {
  __shared__ __align__(16) unsigned short Ks[3][64 * 128];   // 48 KB ring-3
  __shared__ __align__(16) unsigned short Ps[4][32][68];     // 136B rows, 2-way banks
  const int lane = threadIdx.x & 63;
  const int wid = threadIdx.x >> 6;
  const int hi2 = lane >> 5;
  const int ql = lane & 31;
  const int bid = blockIdx.x;
  const int h = bid & 15;
  const int qb = (bid >> 4) & 15;
  const int ksp = bid >> 8;              // 0..1
  const int q0 = qb * 128 + wid * 32;
  const int kbase = ksp * 1024;

  auto stageK = [&](int buf, int kt2) {
#pragma unroll
    for (int r = 0; r < 4; ++r) {
      const int off = r * 4096 + (wid * 64 + lane) * 16;
      const int row = off >> 8;
      const int colb = (off & 255) ^ ((row & 15) << 4);
      gload_lds16(k + ((size_t)h * 2048 + kbase + kt2 * 64 + row) * 128 + (colb >> 1),
                  (char*)Ks[buf] + r * 4096 + wid * 1024);
    }
  };

  bf16x8 qf[8];
  {
    const unsigned short* qp = q + ((size_t)h * 2048 + q0 + ql) * 128 + hi2 * 8;
#pragma unroll
    for (int c = 0; c < 8; ++c) qf[c] = *reinterpret_cast<const bf16x8*>(qp + c * 16);
  }
  f32x16 O[4];
#pragma unroll
  for (int i = 0; i < 4; ++i)
#pragma unroll
    for (int j = 0; j < 16; ++j) O[i][j] = 0.f;
  float m = -1e30f, l = 0.f;

  stageK(0, 0);
  stageK(1, 1);
  asm volatile("s_waitcnt vmcnt(4)" ::: "memory");
  __builtin_amdgcn_s_barrier();

  const int kswz = (lane & 15) << 4;
  for (int kt = 0; kt < 16; ++kt) {
    const int cur = kt % 3;

    f32x16 s0, s1;
#pragma unroll
    for (int j = 0; j < 16; ++j) { s0[j] = 0.f; s1[j] = 0.f; }
    __builtin_amdgcn_s_setprio(1);
#pragma unroll
    for (int c = 0; c < 8; ++c) {
      bf16x8 a0 = *reinterpret_cast<const bf16x8*>(
          (const char*)Ks[cur] + ql * 256 + ((c * 32 + hi2 * 16) ^ kswz));
      s0 = __builtin_amdgcn_mfma_f32_32x32x16_bf16(a0, qf[c], s0, 0, 0, 0);
    }
#pragma unroll
    for (int c = 0; c < 8; ++c) {
      bf16x8 a1 = *reinterpret_cast<const bf16x8*>(
          (const char*)Ks[cur] + (32 + ql) * 256 + ((c * 32 + hi2 * 16) ^ kswz));
      s1 = __builtin_amdgcn_mfma_f32_32x32x16_bf16(a1, qf[c], s1, 0, 0, 0);
    }
    __builtin_amdgcn_s_setprio(0);

    float mt = s0[0];
#pragma unroll
    for (int j = 1; j < 16; ++j) mt = fmaxf(mt, s0[j]);
#pragma unroll
    for (int j = 0; j < 16; ++j) mt = fmaxf(mt, s1[j]);
    mt = fmaxf(mt, __shfl_xor(mt, 32, 64));

    if (!__all(mt <= m + 8.0f)) {          // defer-max
      const float mn = fmaxf(m, mt);
      const float al = __expf(m - mn);
      m = mn;
      l *= al;
#pragma unroll
      for (int i = 0; i < 4; ++i)
#pragma unroll
        for (int j = 0; j < 16; ++j) O[i][j] *= al;
    }
    float rs = 0.f;
#pragma unroll
    for (int j = 0; j < 16; ++j) {
      s0[j] = __expf(s0[j] - m); rs += s0[j];
      s1[j] = __expf(s1[j] - m); rs += s1[j];
    }
    rs += __shfl_xor(rs, 32, 64);
    l += rs;

#pragma unroll
    for (int a = 0; a < 4; ++a) {
      uint2 w0, w1;
      w0.x = (unsigned)f2bf(s0[a * 4 + 0]) | ((unsigned)f2bf(s0[a * 4 + 1]) << 16);
      w0.y = (unsigned)f2bf(s0[a * 4 + 2]) | ((unsigned)f2bf(s0[a * 4 + 3]) << 16);
      w1.x = (unsigned)f2bf(s1[a * 4 + 0]) | ((unsigned)f2bf(s1[a * 4 + 1]) << 16);
      w1.y = (unsigned)f2bf(s1[a * 4 + 2]) | ((unsigned)f2bf(s1[a * 4 + 3]) << 16);
      *reinterpret_cast<uint2*>(&Ps[wid][ql][a * 8 + hi2 * 4]) = w0;
      *reinterpret_cast<uint2*>(&Ps[wid][ql][32 + a * 8 + hi2 * 4]) = w1;
    }
    bf16x8 pf[4];
#pragma unroll
    for (int c2 = 0; c2 < 4; ++c2) {
      uint2 u0 = *reinterpret_cast<const uint2*>(&Ps[wid][ql][c2 * 16 + hi2 * 8]);
      uint2 u1 = *reinterpret_cast<const uint2*>(&Ps[wid][ql][c2 * 16 + hi2 * 8 + 4]);
      union { uint4 u; bf16x8 v; } pu;
      pu.u.x = u0.x; pu.u.y = u0.y; pu.u.z = u1.x; pu.u.w = u1.y;
      pf[c2] = pu.v;
    }

    const int cg0 = (kbase >> 4) + kt * 4;
    __builtin_amdgcn_s_setprio(1);
#pragma unroll
    for (int dblk = 0; dblk < 4; ++dblk) {
#pragma unroll
      for (int c2 = 0; c2 < 4; ++c2) {
        bf16x8 va = *reinterpret_cast<const bf16x8*>(
            vt2 + ((((size_t)h * 128 + cg0 + c2) * 4 + dblk) * 64 + lane) * 8);
        O[dblk] = __builtin_amdgcn_mfma_f32_32x32x16_bf16(va, pf[c2], O[dblk], 0, 0, 0);
      }
    }
    __builtin_amdgcn_s_setprio(0);

    if (kt + 2 < 16) stageK((kt + 2) % 3, kt + 2);
    if (kt + 1 < 16) {
      asm volatile("s_waitcnt vmcnt(4)" ::: "memory");
      __builtin_amdgcn_s_barrier();
    }
  }

  const float rl = 1.0f / l;
  const int n = q0 + ql;
  unsigned short* ob = Onorm + (((size_t)(ksp * 16 + h) * 2048) + n) * 128;
#pragma unroll
  for (int dblk = 0; dblk < 4; ++dblk)
#pragma unroll
    for (int a = 0; a < 4; ++a) {
      uint2 w;
      w.x = (unsigned)f2bf(O[dblk][a * 4 + 0] * rl) | ((unsigned)f2bf(O[dblk][a * 4 + 1] * rl) << 16);
      w.y = (unsigned)f2bf(O[dblk][a * 4 + 2] * rl) | ((unsigned)f2bf(O[dblk][a * 4 + 3] * rl) << 16);
      *reinterpret_cast<uint2*>(ob + dblk * 32 + a * 8 + hi2 * 4) = w;
    }
  if (hi2 == 0)
    lseb[(size_t)(ksp * 16 + h) * 2048 + n] = m + logf(l);
}

// ============ 6. merge the two key-split partials ============
__global__ __launch_bounds__(256) void k_merge(const unsigned short* __restrict__ Onorm,
                                               const float* __restrict__ lseb,
                                               unsigned short* __restrict__ att) {
  const int idx = blockIdx.x * 256 + threadIdx.x;
  const int n = idx >> 8;
  const int r = idx & 255;
  const int h = r >> 4;
  const int d0 = (r & 15) * 8;
  const float l0 = lseb[(size_t)h * 2048 + n];
  const float l1 = lseb[(size_t)(16 + h) * 2048 + n];
  const float M = fmaxf(l0, l1);
  float w0 = __expf(l0 - M), w1 = __expf(l1 - M);
  const float inv = 1.0f / (w0 + w1);
  w0 *= inv; w1 *= inv;
  const bf16x8 o0 = *reinterpret_cast<const bf16x8*>(
      Onorm + ((size_t)h * 2048 + n) * 128 + d0);
  const bf16x8 o1 = *reinterpret_cast<const bf16x8*>(
      Onorm + ((size_t)(16 + h) * 2048 + n) * 128 + d0);
  bf16x8 o;
#pragma unroll
  for (int e = 0; e < 8; ++e)
    o[e] = (short)f2bf(bf2f((unsigned short)o0[e]) * w0 + bf2f((unsigned short)o1[e]) * w1);
  *reinterpret_cast<bf16x8*>(att + (size_t)n * 2048 + h * 128 + d0) = o;
}

extern "C" void kernel_launch(void* const* d_in, const int* in_sizes, int n_in,
                              void* d_out, int out_size, void* d_ws, size_t ws_size,
                              hipStream_t stream) {
  (void)in_sizes; (void)n_in; (void)out_size; (void)ws_size;
  const float* x      = (const float*)d_in[0];
  const float* qkv_w  = (const float*)d_in[1];
  const float* qkv_b  = (const float*)d_in[2];
  const float* proj_w = (const float*)d_in[3];
  const float* proj_b = (const float*)d_in[4];
  const float* q_nw   = (const float*)d_in[5];
  const float* k_nw   = (const float*)d_in[6];
  const int* h_dim    = (const int*)d_in[8];
  const int* w_dim    = (const int*)d_in[9];
  float* out = (float*)d_out;

  char* ws = (char*)d_ws;
  size_t off = 0;
  auto carve = [&](size_t bytes) -> void* {
    void* p = ws + off;
    off += (bytes + 255) & ~(size_t)255;
    return p;
  };
  unsigned short* x_bf   = (unsigned short*)carve(2048ull * 2048 * 2);
  unsigned short* w1_bf  = (unsigned short*)carve(6144ull * 2048 * 2);
  unsigned short* w2_bf  = (unsigned short*)carve(2048ull * 2048 * 2);
  unsigned short* qkvb   = (unsigned short*)carve(2048ull * 6144 * 2);
  unsigned short* q_bf   = (unsigned short*)carve(16ull * 2048 * 128 * 2);
  unsigned short* k_bf   = (unsigned short*)carve(16ull * 2048 * 128 * 2);
  unsigned short* vt2_bf = (unsigned short*)carve(16ull * 2048 * 128 * 2);
  unsigned short* att_bf = (unsigned short*)carve(2048ull * 2048 * 2);
  unsigned short* on_bf  = (unsigned short*)carve(2ull * 16 * 2048 * 128 * 2);
  float*          lseb   = (float*)carve(2ull * 16 * 2048 * 4);
  float*          projp  = (float*)carve(2ull * 2048 * 2048 * 4);
  float*          cosT   = (float*)carve(2048ull * 64 * 4);
  float*          sinT   = (float*)carve(2048ull * 64 * 4);

  hipLaunchKernelGGL(k_cvt_bf16, dim3(2048), dim3(256), 0, stream, x, x_bf, 2048 * 2048 / 4);
  hipLaunchKernelGGL(k_cvt_bf16, dim3(2048), dim3(256), 0, stream, qkv_w, w1_bf, 6144 * 2048 / 4);
  hipLaunchKernelGGL(k_cvt_bf16, dim3(2048), dim3(256), 0, stream, proj_w, w2_bf, 2048 * 2048 / 4);
  hipLaunchKernelGGL(k_rope_tab, dim3(512), dim3(256), 0, stream, cosT, sinT, h_dim, w_dim);
  // QKV: 128x192 tiles -> grid 16x32 = 512 blocks, 2 blocks/CU
  hipLaunchKernelGGL(k_gemmQKV, dim3(512), dim3(256), 0, stream,
                     x_bf, w1_bf, qkv_b, qkvb, 2048, 6144, 2048);
  hipLaunchKernelGGL(k_qk_post, dim3(8192), dim3(256), 0, stream,
                     qkvb, q_nw, k_nw, cosT, sinT, q_bf, k_bf);
  hipLaunchKernelGGL(k_v_tr, dim3(32, 16), dim3(256), 0, stream, qkvb, vt2_bf);
  hipLaunchKernelGGL(k_fattn, dim3(512), dim3(256), 0, stream,
                     q_bf, k_bf, vt2_bf, on_bf, lseb);
  hipLaunchKernelGGL(k_merge, dim3(2048), dim3(256), 0, stream, on_bf, lseb, att_bf);
  hipLaunchKernelGGL(k_gemm_bt_sk, dim3(16, 16, 2), dim3(256), 0, stream,
                     att_bf, w2_bf, projp, 2048, 2048, 2048, 1024);
  hipLaunchKernelGGL(k_addbias, dim3(4096), dim3(256), 0, stream, projp, proj_b, out);
}

// Round 13
// 186.311 us; speedup vs baseline: 1.2071x; 1.0960x over previous
//
#include <hip/hip_runtime.h>
#include <hip/hip_bf16.h>
#include <cstdint>
#include <cstddef>

typedef __attribute__((ext_vector_type(8))) short bf16x8;
typedef __attribute__((ext_vector_type(4))) float f32x4;
typedef __attribute__((ext_vector_type(16))) float f32x16;

#define AS1 __attribute__((address_space(1)))
#define AS3 __attribute__((address_space(3)))

__device__ __forceinline__ void gload_lds16(const void* g, void* l) {
  __builtin_amdgcn_global_load_lds((const AS1 void*)g, (AS3 void*)l, 16, 0, 0);
}

__device__ __forceinline__ unsigned short f2bf(float x) {
  __hip_bfloat16 h = __float2bfloat16(x);
  return __builtin_bit_cast(unsigned short, h);
}
__device__ __forceinline__ float bf2f(unsigned short u) {
  return __builtin_bit_cast(float, (unsigned int)u << 16);
}
// pack two f32 -> one u32 of 2x bf16 (lo = a, hi = b)
__device__ __forceinline__ unsigned cvtpk(float a, float b) {
  unsigned r;
  asm("v_cvt_pk_bf16_f32 %0, %1, %2" : "=v"(r) : "v"(a), "v"(b));
  return r;
}
// v_permlane32_swap_b32 vdst, vsrc: vdst[lanes 32..63] <-> vsrc[lanes 0..31]
__device__ __forceinline__ void pswap(unsigned& x, unsigned& y) {
  asm volatile("v_permlane32_swap_b32 %0, %1" : "+v"(x), "+v"(y));
}

// ============ 1. f32 -> bf16 convert ============
__global__ __launch_bounds__(256) void k_cvt_bf16(const float* __restrict__ in,
                                                  unsigned short* __restrict__ out,
                                                  int n4) {
  int i = blockIdx.x * 256 + threadIdx.x;
  const int stride = gridDim.x * 256;
  for (; i < n4; i += stride) {
    float4 v = reinterpret_cast<const float4*>(in)[i];
    ushort4 o;
    o.x = f2bf(v.x); o.y = f2bf(v.y); o.z = f2bf(v.z); o.w = f2bf(v.w);
    reinterpret_cast<ushort4*>(out)[i] = o;
  }
}

// ============ 2. RoPE cos/sin tables [2048][64] ============
__global__ __launch_bounds__(256) void k_rope_tab(float* __restrict__ cosT,
                                                  float* __restrict__ sinT,
                                                  const int* __restrict__ hdim,
                                                  const int* __restrict__ wdim) {
  int idx = blockIdx.x * 256 + threadIdx.x;
  if (idx >= 2048 * 64) return;
  const int n = idx >> 6, j = idx & 63;
  const int H = *hdim, W = *wdim;
  const int w = n % W;
  const int rem = n / W;
  const int h = rem % H;
  const int t = rem / H;
  float pos, i2, d;
  if (j < 22)      { pos = (float)t; i2 = (float)(2 * j);        d = 44.f; }
  else if (j < 43) { pos = (float)h; i2 = (float)(2 * (j - 22)); d = 42.f; }
  else             { pos = (float)w; i2 = (float)(2 * (j - 43)); d = 42.f; }
  const float ang = pos * powf(10000.0f, -i2 / d);
  cosT[idx] = cosf(ang);
  sinT[idx] = sinf(ang);
}

// ============ 3a. QKV GEMM: 128x192 tile, BK=64, 2-phase counted-vmcnt (unchanged)
__global__ __launch_bounds__(256, 2) void k_gemmQKV(const unsigned short* __restrict__ A,
                                                    const unsigned short* __restrict__ B,
                                                    const float* __restrict__ bias,
                                                    unsigned short* __restrict__ C,
                                                    int M, int N, int K) {
  __shared__ __align__(16) char lds[81920];
  const int tid = threadIdx.x;
  const int lane = tid & 63;
  const int wid = tid >> 6;
  const int wr = wid >> 1, wc = wid & 1;

  const int xcd = blockIdx.x & 7;
  const int t = blockIdx.x >> 3;
  const int bx = xcd * 4 + (t & 3);
  const int by = t >> 2;
  const int row0 = by * 128, col0 = bx * 192;
  const int NT = K >> 6;

  auto stageA = [&](int grow0, int kcol0, char* slot) {
#pragma unroll
    for (int r = 0; r < 2; ++r) {
      const int off = r * 4096 + tid * 16;
      const int pair = off >> 7;
      const int un = (off & 127) ^ ((pair & 7) << 4);
      const int grow = pair * 2 + (un >> 6);
      gload_lds16(A + (size_t)(grow0 + grow) * K + kcol0 + ((un & 63) >> 1),
                  slot + r * 4096 + wid * 1024);
    }
  };
  auto stageB = [&](int grow0, int kcol0, char* slot) {
#pragma unroll
    for (int r = 0; r < 3; ++r) {
      const int off = r * 4096 + tid * 16;
      const int pair = off >> 7;
      const int un = (off & 127) ^ ((pair & 7) << 4);
      const int grow = pair * 2 + (un >> 6);
      gload_lds16(B + (size_t)(grow0 + grow) * K + kcol0 + ((un & 63) >> 1),
                  slot + r * 4096 + wid * 1024);
    }
  };
  auto frag = [&](const char* slot, int r, int kb) -> bf16x8 {
    return *reinterpret_cast<const bf16x8*>(
        slot + (r >> 1) * 128 + ((((r & 1) << 6) + kb) ^ (((r >> 1) & 7) << 4)));
  };

  f32x4 acc[4][6];
#pragma unroll
  for (int i = 0; i < 4; ++i)
#pragma unroll
    for (int j = 0; j < 6; ++j) acc[i][j] = (f32x4){0.f, 0.f, 0.f, 0.f};

  stageA(row0, 0,  lds);
  stageB(col0, 0,  lds + 16384);
  stageA(row0, 32, lds + 8192);
  stageB(col0, 32, lds + 28672);
  asm volatile("s_waitcnt vmcnt(5)" ::: "memory");
  __builtin_amdgcn_s_barrier();

  const int kb = (lane >> 4) << 4;
  for (int j = 0; j < NT; ++j) {
    const int b = j & 1, bp = b ^ 1;
    const char* base = lds + b * 40960;
    char* pbase = lds + bp * 40960;
    const bool pf = (j + 1 < NT);
    const int kn = (j + 1) * 64;
    bf16x8 af[4], bq[6];

#pragma unroll
    for (int fr = 0; fr < 4; ++fr) af[fr] = frag(base, wr * 64 + fr * 16 + (lane & 15), kb);
#pragma unroll
    for (int fc = 0; fc < 6; ++fc) bq[fc] = frag(base + 16384, wc * 96 + fc * 16 + (lane & 15), kb);
    if (pf) { stageA(row0, kn, pbase); stageB(col0, kn, pbase + 16384); }
    if (pf) asm volatile("s_waitcnt vmcnt(5)" ::: "memory");
    else    asm volatile("s_waitcnt vmcnt(0)" ::: "memory");
    __builtin_amdgcn_s_barrier();
    __builtin_amdgcn_s_setprio(1);
#pragma unroll
    for (int fr = 0; fr < 4; ++fr)
#pragma unroll
      for (int fc = 0; fc < 6; ++fc)
        acc[fr][fc] = __builtin_amdgcn_mfma_f32_16x16x32_bf16(af[fr], bq[fc], acc[fr][fc], 0, 0, 0);
    __builtin_amdgcn_s_setprio(0);
    __builtin_amdgcn_s_barrier();

#pragma unroll
    for (int fr = 0; fr < 4; ++fr) af[fr] = frag(base + 8192, wr * 64 + fr * 16 + (lane & 15), kb);
#pragma unroll
    for (int fc = 0; fc < 6; ++fc) bq[fc] = frag(base + 28672, wc * 96 + fc * 16 + (lane & 15), kb);
    if (pf) { stageA(row0, kn + 32, pbase + 8192); stageB(col0, kn + 32, pbase + 28672); }
    if (pf) asm volatile("s_waitcnt vmcnt(5)" ::: "memory");
    __builtin_amdgcn_s_barrier();
    __builtin_amdgcn_s_setprio(1);
#pragma unroll
    for (int fr = 0; fr < 4; ++fr)
#pragma unroll
      for (int fc = 0; fc < 6; ++fc)
        acc[fr][fc] = __builtin_amdgcn_mfma_f32_16x16x32_bf16(af[fr], bq[fc], acc[fr][fc], 0, 0, 0);
    __builtin_amdgcn_s_setprio(0);
    __builtin_amdgcn_s_barrier();
  }

#pragma unroll
  for (int fr = 0; fr < 4; ++fr)
#pragma unroll
    for (int fc = 0; fc < 6; ++fc) {
      const int col = col0 + wc * 96 + fc * 16 + (lane & 15);
      const float bv = bias[col];
#pragma unroll
      for (int jj = 0; jj < 4; ++jj) {
        const int row = row0 + wr * 64 + fr * 16 + (lane >> 4) * 4 + jj;
        C[(size_t)row * N + col] = f2bf(acc[fr][fc][jj] + bv);
      }
    }
}

// ============ 3b. 128x128 m97-structure GEMM with split-K (proj) ====
__global__ __launch_bounds__(256) void k_gemm_bt_sk(const unsigned short* __restrict__ A,
                                                    const unsigned short* __restrict__ B,
                                                    float* __restrict__ Cp,
                                                    int M, int N, int K, int KS) {
  __shared__ __align__(16) unsigned short As[128 * 32];
  __shared__ __align__(16) unsigned short Bs[128 * 32];
  const int lane = threadIdx.x & 63;
  const int wid  = threadIdx.x >> 6;
  const int wr = wid >> 1, wc = wid & 1;
  const int rowA0 = blockIdx.y * 128;
  const int rowB0 = blockIdx.x * 128;
  const int k0 = blockIdx.z * KS;

  f32x4 acc[4][4];
#pragma unroll
  for (int i = 0; i < 4; ++i)
#pragma unroll
    for (int j = 0; j < 4; ++j) acc[i][j] = (f32x4){0.f, 0.f, 0.f, 0.f};

  for (int kt = k0; kt < k0 + KS; kt += 32) {
#pragma unroll
    for (int i = 0; i < 2; ++i) {
      const int c = i * 4 + wid;
      const int off = c * 1024 + lane * 16;
      const int row = off >> 6;
      const int col = (off & 63) >> 1;
      gload_lds16(A + (size_t)(rowA0 + row) * K + kt + col, (char*)As + c * 1024);
      gload_lds16(B + (size_t)(rowB0 + row) * K + kt + col, (char*)Bs + c * 1024);
    }
    __syncthreads();
    bf16x8 af[4], bfr[4];
#pragma unroll
    for (int mi = 0; mi < 4; ++mi)
      af[mi] = *reinterpret_cast<const bf16x8*>(
          &As[(wr * 64 + mi * 16 + (lane & 15)) * 32 + (lane >> 4) * 8]);
#pragma unroll
    for (int ni = 0; ni < 4; ++ni)
      bfr[ni] = *reinterpret_cast<const bf16x8*>(
          &Bs[(wc * 64 + ni * 16 + (lane & 15)) * 32 + (lane >> 4) * 8]);
#pragma unroll
    for (int mi = 0; mi < 4; ++mi)
#pragma unroll
      for (int ni = 0; ni < 4; ++ni)
        acc[mi][ni] = __builtin_amdgcn_mfma_f32_16x16x32_bf16(af[mi], bfr[ni], acc[mi][ni], 0, 0, 0);
    __syncthreads();
  }

  float* Cz = Cp + (size_t)blockIdx.z * M * N;
#pragma unroll
  for (int mi = 0; mi < 4; ++mi)
#pragma unroll
    for (int ni = 0; ni < 4; ++ni) {
      const int col = rowB0 + wc * 64 + ni * 16 + (lane & 15);
#pragma unroll
      for (int j = 0; j < 4; ++j) {
        const int row = rowA0 + wr * 64 + mi * 16 + (lane >> 4) * 4 + j;
        Cz[(size_t)row * N + col] = acc[mi][ni][j];
      }
    }
}

// ============ 3c. sum split-K partials + bias -> f32 out ============
__global__ __launch_bounds__(256) void k_addbias(const float* __restrict__ Cp,
                                                 const float* __restrict__ bias,
                                                 float* __restrict__ out) {
  const int i = blockIdx.x * 256 + threadIdx.x;
  const float4 a = reinterpret_cast<const float4*>(Cp)[i];
  const float4 b = reinterpret_cast<const float4*>(Cp + 2048ull * 2048)[i];
  const float4 bv = reinterpret_cast<const float4*>(bias)[i & 511];
  float4 o;
  o.x = a.x + b.x + bv.x; o.y = a.y + b.y + bv.y;
  o.z = a.z + b.z + bv.z; o.w = a.w + b.w + bv.w;
  reinterpret_cast<float4*>(out)[i] = o;
}

// ============ 4a. q/k: RMSNorm + RoPE + (q: fold scale) from bf16 qkv ============
__global__ __launch_bounds__(256) void k_qk_post(const unsigned short* __restrict__ qkv,
                                                 const float* __restrict__ qw,
                                                 const float* __restrict__ kw,
                                                 const float* __restrict__ cosT,
                                                 const float* __restrict__ sinT,
                                                 unsigned short* __restrict__ qo,
                                                 unsigned short* __restrict__ ko) {
  const int lane = threadIdx.x & 63;
  const int wid = threadIdx.x >> 6;
  const int pair = blockIdx.x * 4 + wid;
  const int n = pair >> 4, h = pair & 15;
  const float c = cosT[n * 64 + lane];
  const float s = sinT[n * 64 + lane];
#pragma unroll
  for (int sq = 0; sq < 2; ++sq) {
    const unsigned short* src = qkv + (size_t)n * 6144 + sq * 2048 + h * 128;
    const unsigned int vp = reinterpret_cast<const unsigned int*>(src)[lane];
    const float vx = bf2f((unsigned short)(vp & 0xffff));
    const float vy = bf2f((unsigned short)(vp >> 16));
    float ss = vx * vx + vy * vy;
#pragma unroll
    for (int m = 1; m < 64; m <<= 1) ss += __shfl_xor(ss, m, 64);
    const float r = rsqrtf(ss * (1.0f / 128.0f) + 1e-6f);
    float2 wv = reinterpret_cast<const float2*>(sq == 0 ? qw : kw)[lane];
    const float xr = vx * r * wv.x;
    const float xi = vy * r * wv.y;
    float orr = xr * c - xi * s;
    float oi  = xr * s + xi * c;
    if (sq == 0) { orr *= 0.08838834764831845f; oi *= 0.08838834764831845f; }
    unsigned short* dst = (sq == 0 ? qo : ko) + ((size_t)h * 2048 + n) * 128 + 2 * lane;
    const unsigned int pk = (unsigned int)f2bf(orr) | ((unsigned int)f2bf(oi) << 16);
    *reinterpret_cast<unsigned int*>(dst) = pk;
  }
}

// ============ 4b. v: bf16 qkv -> vt2, MFMA-fragment-ordered (lane-direct) ====
__global__ __launch_bounds__(256) void k_v_tr(const unsigned short* __restrict__ qkv,
                                              unsigned short* __restrict__ vt2) {
  __shared__ __align__(16) unsigned short tile[64][136];
  const int h = blockIdx.y;
  const int n0 = blockIdx.x * 64;
  const int t = threadIdx.x;
  {
    const int row = t >> 2;
    const int c0 = (t & 3) * 32;
    const unsigned short* src = qkv + (size_t)(n0 + row) * 6144 + 4096 + h * 128 + c0;
#pragma unroll
    for (int j = 0; j < 32; j += 8)
      *reinterpret_cast<bf16x8*>(&tile[row][c0 + j]) =
          *reinterpret_cast<const bf16x8*>(src + j);
  }
  __syncthreads();
#pragma unroll
  for (int g4 = 0; g4 < 4; ++g4) {
    const int g = g4 * 256 + t;
    const int c = g >> 8;
    const int dblk = (g >> 6) & 3;
    const int p = g & 63;
    const int d = dblk * 32 + (p & 31);
    const int hi = p >> 5;
    bf16x8 o;
#pragma unroll
    for (int e = 0; e < 8; ++e) o[e] = (short)tile[c * 16 + hi * 8 + e][d];
    const size_t oidx = ((((size_t)h * 128 + (n0 >> 4) + c) * 4 + dblk) * 64 + p) * 8;
    *reinterpret_cast<bf16x8*>(vt2 + oidx) = o;
  }
}

// ============ 5. flash attention v7b: T12 in-register P (cvt_pk + permlane32_swap,
// operand order per HW semantic: vdst[32:63] <-> vsrc[0:31]), K+V LDS ring-2.
__global__ __launch_bounds__(256) void k_fattn(const unsigned short* __restrict__ q,
                                               const unsigned short* __restrict__ k,
                                               const unsigned short* __restrict__ vt2,
                                               unsigned short* __restrict__ Onorm,
                                               float* __restrict__ lseb) {
  __shared__ __align__(16) unsigned short Ks[2][64 * 128];   // 32 KB
  __shared__ __align__(16) unsigned short Vs[2][64 * 128];   // 32 KB (16KB/tile, linear copy)
  const int lane = threadIdx.x & 63;
  const int wid = threadIdx.x >> 6;
  const int hi2 = lane >> 5;
  const int ql = lane & 31;
  const int bid = blockIdx.x;
  const int h = bid & 15;
  const int qb = (bid >> 4) & 15;
  const int ksp = bid >> 8;              // 0..1
  const int q0 = qb * 128 + wid * 32;
  const int kbase = ksp * 1024;

  auto stageK = [&](int buf, int kt2) {
#pragma unroll
    for (int r = 0; r < 4; ++r) {
      const int off = r * 4096 + (wid * 64 + lane) * 16;
      const int row = off >> 8;
      const int colb = (off & 255) ^ ((row & 15) << 4);
      gload_lds16(k + ((size_t)h * 2048 + kbase + kt2 * 64 + row) * 128 + (colb >> 1),
                  (char*)Ks[buf] + r * 4096 + wid * 1024);
    }
  };
  // V tile kt2 is 16KB contiguous in vt2, read order == linear lane order.
  auto stageV = [&](int buf, int kt2) {
    const unsigned short* vbase = vt2 + ((size_t)h * 128 + (kbase >> 4) + kt2 * 4) * 2048;
#pragma unroll
    for (int r = 0; r < 4; ++r)
      gload_lds16(vbase + r * 2048 + (wid * 64 + lane) * 8,
                  (char*)Vs[buf] + r * 4096 + wid * 1024);
  };

  bf16x8 qf[8];
  {
    const unsigned short* qp = q + ((size_t)h * 2048 + q0 + ql) * 128 + hi2 * 8;
#pragma unroll
    for (int c = 0; c < 8; ++c) qf[c] = *reinterpret_cast<const bf16x8*>(qp + c * 16);
  }
  f32x16 O[4];
#pragma unroll
  for (int i = 0; i < 4; ++i)
#pragma unroll
    for (int j = 0; j < 16; ++j) O[i][j] = 0.f;
  float m = -1e30f, l = 0.f;

  stageK(0, 0);
  stageV(0, 0);
  asm volatile("s_waitcnt vmcnt(0)" ::: "memory");
  __builtin_amdgcn_s_barrier();

  const int kswz = (lane & 15) << 4;
  for (int kt = 0; kt < 16; ++kt) {
    const int cur = kt & 1;
    const bool pf = (kt + 1 < 16);
    if (pf) { stageK(cur ^ 1, kt + 1); stageV(cur ^ 1, kt + 1); }

    f32x16 s0, s1;
#pragma unroll
    for (int j = 0; j < 16; ++j) { s0[j] = 0.f; s1[j] = 0.f; }
    __builtin_amdgcn_s_setprio(1);
#pragma unroll
    for (int c = 0; c < 8; ++c) {
      bf16x8 a0 = *reinterpret_cast<const bf16x8*>(
          (const char*)Ks[cur] + ql * 256 + ((c * 32 + hi2 * 16) ^ kswz));
      s0 = __builtin_amdgcn_mfma_f32_32x32x16_bf16(a0, qf[c], s0, 0, 0, 0);
    }
#pragma unroll
    for (int c = 0; c < 8; ++c) {
      bf16x8 a1 = *reinterpret_cast<const bf16x8*>(
          (const char*)Ks[cur] + (32 + ql) * 256 + ((c * 32 + hi2 * 16) ^ kswz));
      s1 = __builtin_amdgcn_mfma_f32_32x32x16_bf16(a1, qf[c], s1, 0, 0, 0);
    }
    __builtin_amdgcn_s_setprio(0);
    // lane (q = lane&31, g = lane>>5) holds key (j&3) + 8*(j>>2) + 4*g  (+32 for s1)

    float mt = s0[0];
#pragma unroll
    for (int j = 1; j < 16; ++j) mt = fmaxf(mt, s0[j]);
#pragma unroll
    for (int j = 0; j < 16; ++j) mt = fmaxf(mt, s1[j]);
    mt = fmaxf(mt, __shfl_xor(mt, 32, 64));

    if (!__all(mt <= m + 8.0f)) {          // defer-max
      const float mn = fmaxf(m, mt);
      const float al = __expf(m - mn);
      m = mn;
      l *= al;
#pragma unroll
      for (int i = 0; i < 4; ++i)
#pragma unroll
        for (int j = 0; j < 16; ++j) O[i][j] *= al;
    }
    float rs = 0.f;
#pragma unroll
    for (int j = 0; j < 16; ++j) {
      s0[j] = __expf(s0[j] - m); rs += s0[j];
      s1[j] = __expf(s1[j] - m); rs += s1[j];
    }
    rs += __shfl_xor(rs, 32, 64);
    l += rs;

    // T12: in-register P^T -> PV B-frags.
    // a[j2] = pack(P(2j2), P(2j2+1)); keys of a: hi2=0: {0,1},{2,3},{8,9},{10,11},
    // {16,17},{18,19},{24,25},{26,27}; hi2=1: +4.
    // HW: pswap(x,y): x[l>=32] <-> y[l<32].
    // pswap(a0,a2): a0[hi] <- a2[lo] = keys{8,9} (w0 for hi2=1);
    //               a2[lo] <- a0[hi] = keys{4,5} (w2 for hi2=0).  etc.
    bf16x8 pfr[4];
#pragma unroll
    for (int half = 0; half < 2; ++half) {
      const f32x16& sv = half ? s1 : s0;
      unsigned a[8];
#pragma unroll
      for (int j2 = 0; j2 < 8; ++j2) a[j2] = cvtpk(sv[2 * j2], sv[2 * j2 + 1]);
      pswap(a[0], a[2]);
      pswap(a[1], a[3]);
      pswap(a[4], a[6]);
      pswap(a[5], a[7]);
      union { uint4 u; bf16x8 v; } p0, p1;
      p0.u.x = a[0]; p0.u.y = a[1]; p0.u.z = a[2]; p0.u.w = a[3];
      p1.u.x = a[4]; p1.u.y = a[5]; p1.u.z = a[6]; p1.u.w = a[7];
      pfr[half * 2 + 0] = p0.v;
      pfr[half * 2 + 1] = p1.v;
    }

    __builtin_amdgcn_s_setprio(1);
#pragma unroll
    for (int dblk = 0; dblk < 4; ++dblk) {
#pragma unroll
      for (int c2 = 0; c2 < 4; ++c2) {
        bf16x8 va = *reinterpret_cast<const bf16x8*>(
            (const char*)Vs[cur] + ((c2 * 4 + dblk) * 64 + lane) * 16);
        O[dblk] = __builtin_amdgcn_mfma_f32_32x32x16_bf16(va, pfr[c2], O[dblk], 0, 0, 0);
      }
    }
    __builtin_amdgcn_s_setprio(0);

    if (pf) {
      asm volatile("s_waitcnt vmcnt(0)" ::: "memory");
      __builtin_amdgcn_s_barrier();
    }
  }

  const float rl = 1.0f / l;
  const int n = q0 + ql;
  unsigned short* ob = Onorm + (((size_t)(ksp * 16 + h) * 2048) + n) * 128;
#pragma unroll
  for (int dblk = 0; dblk < 4; ++dblk)
#pragma unroll
    for (int a = 0; a < 4; ++a) {
      uint2 w;
      w.x = (unsigned)f2bf(O[dblk][a * 4 + 0] * rl) | ((unsigned)f2bf(O[dblk][a * 4 + 1] * rl) << 16);
      w.y = (unsigned)f2bf(O[dblk][a * 4 + 2] * rl) | ((unsigned)f2bf(O[dblk][a * 4 + 3] * rl) << 16);
      *reinterpret_cast<uint2*>(ob + dblk * 32 + a * 8 + hi2 * 4) = w;
    }
  if (hi2 == 0)
    lseb[(size_t)(ksp * 16 + h) * 2048 + n] = m + logf(l);
}

// ============ 6. merge the two key-split partials ============
__global__ __launch_bounds__(256) void k_merge(const unsigned short* __restrict__ Onorm,
                                               const float* __restrict__ lseb,
                                               unsigned short* __restrict__ att) {
  const int idx = blockIdx.x * 256 + threadIdx.x;
  const int n = idx >> 8;
  const int r = idx & 255;
  const int h = r >> 4;
  const int d0 = (r & 15) * 8;
  const float l0 = lseb[(size_t)h * 2048 + n];
  const float l1 = lseb[(size_t)(16 + h) * 2048 + n];
  const float M = fmaxf(l0, l1);
  float w0 = __expf(l0 - M), w1 = __expf(l1 - M);
  const float inv = 1.0f / (w0 + w1);
  w0 *= inv; w1 *= inv;
  const bf16x8 o0 = *reinterpret_cast<const bf16x8*>(
      Onorm + ((size_t)h * 2048 + n) * 128 + d0);
  const bf16x8 o1 = *reinterpret_cast<const bf16x8*>(
      Onorm + ((size_t)(16 + h) * 2048 + n) * 128 + d0);
  bf16x8 o;
#pragma unroll
  for (int e = 0; e < 8; ++e)
    o[e] = (short)f2bf(bf2f((unsigned short)o0[e]) * w0 + bf2f((unsigned short)o1[e]) * w1);
  *reinterpret_cast<bf16x8*>(att + (size_t)n * 2048 + h * 128 + d0) = o;
}

extern "C" void kernel_launch(void* const* d_in, const int* in_sizes, int n_in,
                              void* d_out, int out_size, void* d_ws, size_t ws_size,
                              hipStream_t stream) {
  (void)in_sizes; (void)n_in; (void)out_size; (void)ws_size;
  const float* x      = (const float*)d_in[0];
  const float* qkv_w  = (const float*)d_in[1];
  const float* qkv_b  = (const float*)d_in[2];
  const float* proj_w = (const float*)d_in[3];
  const float* proj_b = (const float*)d_in[4];
  const float* q_nw   = (const float*)d_in[5];
  const float* k_nw   = (const float*)d_in[6];
  const int* h_dim    = (const int*)d_in[8];
  const int* w_dim    = (const int*)d_in[9];
  float* out = (float*)d_out;

  char* ws = (char*)d_ws;
  size_t off = 0;
  auto carve = [&](size_t bytes) -> void* {
    void* p = ws + off;
    off += (bytes + 255) & ~(size_t)255;
    return p;
  };
  unsigned short* x_bf   = (unsigned short*)carve(2048ull * 2048 * 2);
  unsigned short* w1_bf  = (unsigned short*)carve(6144ull * 2048 * 2);
  unsigned short* w2_bf  = (unsigned short*)carve(2048ull * 2048 * 2);
  unsigned short* qkvb   = (unsigned short*)carve(2048ull * 6144 * 2);
  unsigned short* q_bf   = (unsigned short*)carve(16ull * 2048 * 128 * 2);
  unsigned short* k_bf   = (unsigned short*)carve(16ull * 2048 * 128 * 2);
  unsigned short* vt2_bf = (unsigned short*)carve(16ull * 2048 * 128 * 2);
  unsigned short* att_bf = (unsigned short*)carve(2048ull * 2048 * 2);
  unsigned short* on_bf  = (unsigned short*)carve(2ull * 16 * 2048 * 128 * 2);
  float*          lseb   = (float*)carve(2ull * 16 * 2048 * 4);
  float*          projp  = (float*)carve(2ull * 2048 * 2048 * 4);
  float*          cosT   = (float*)carve(2048ull * 64 * 4);
  float*          sinT   = (float*)carve(2048ull * 64 * 4);

  hipLaunchKernelGGL(k_cvt_bf16, dim3(2048), dim3(256), 0, stream, x, x_bf, 2048 * 2048 / 4);
  hipLaunchKernelGGL(k_cvt_bf16, dim3(2048), dim3(256), 0, stream, qkv_w, w1_bf, 6144 * 2048 / 4);
  hipLaunchKernelGGL(k_cvt_bf16, dim3(2048), dim3(256), 0, stream, proj_w, w2_bf, 2048 * 2048 / 4);
  hipLaunchKernelGGL(k_rope_tab, dim3(512), dim3(256), 0, stream, cosT, sinT, h_dim, w_dim);
  hipLaunchKernelGGL(k_gemmQKV, dim3(512), dim3(256), 0, stream,
                     x_bf, w1_bf, qkv_b, qkvb, 2048, 6144, 2048);
  hipLaunchKernelGGL(k_qk_post, dim3(8192), dim3(256), 0, stream,
                     qkvb, q_nw, k_nw, cosT, sinT, q_bf, k_bf);
  hipLaunchKernelGGL(k_v_tr, dim3(32, 16), dim3(256), 0, stream, qkvb, vt2_bf);
  hipLaunchKernelGGL(k_fattn, dim3(512), dim3(256), 0, stream,
                     q_bf, k_bf, vt2_bf, on_bf, lseb);
  hipLaunchKernelGGL(k_merge, dim3(2048), dim3(256), 0, stream, on_bf, lseb, att_bf);
  hipLaunchKernelGGL(k_gemm_bt_sk, dim3(16, 16, 2), dim3(256), 0, stream,
                     att_bf, w2_bf, projp, 2048, 2048, 2048, 1024);
  hipLaunchKernelGGL(k_addbias, dim3(4096), dim3(256), 0, stream, projp, proj_b, out);
}

// Round 14
// 177.612 us; speedup vs baseline: 1.2662x; 1.0490x over previous
//
#include <hip/hip_runtime.h>
#include <hip/hip_bf16.h>
#include <cstdint>
#include <cstddef>

typedef __attribute__((ext_vector_type(8))) short bf16x8;
typedef __attribute__((ext_vector_type(4))) float f32x4;
typedef __attribute__((ext_vector_type(16))) float f32x16;

#define AS1 __attribute__((address_space(1)))
#define AS3 __attribute__((address_space(3)))

__device__ __forceinline__ void gload_lds16(const void* g, void* l) {
  __builtin_amdgcn_global_load_lds((const AS1 void*)g, (AS3 void*)l, 16, 0, 0);
}

__device__ __forceinline__ unsigned short f2bf(float x) {
  __hip_bfloat16 h = __float2bfloat16(x);
  return __builtin_bit_cast(unsigned short, h);
}
__device__ __forceinline__ float bf2f(unsigned short u) {
  return __builtin_bit_cast(float, (unsigned int)u << 16);
}
__device__ __forceinline__ unsigned cvtpk(float a, float b) {
  unsigned r;
  asm("v_cvt_pk_bf16_f32 %0, %1, %2" : "=v"(r) : "v"(a), "v"(b));
  return r;
}
// v_permlane32_swap_b32 vdst, vsrc: vdst[lanes 32..63] <-> vsrc[lanes 0..31]
__device__ __forceinline__ void pswap(unsigned& x, unsigned& y) {
  asm volatile("v_permlane32_swap_b32 %0, %1" : "+v"(x), "+v"(y));
}

// ============ 1. f32 -> bf16 convert ============
__global__ __launch_bounds__(256) void k_cvt_bf16(const float* __restrict__ in,
                                                  unsigned short* __restrict__ out,
                                                  int n4) {
  int i = blockIdx.x * 256 + threadIdx.x;
  const int stride = gridDim.x * 256;
  for (; i < n4; i += stride) {
    float4 v = reinterpret_cast<const float4*>(in)[i];
    ushort4 o;
    o.x = f2bf(v.x); o.y = f2bf(v.y); o.z = f2bf(v.z); o.w = f2bf(v.w);
    reinterpret_cast<ushort4*>(out)[i] = o;
  }
}

// ============ 2. RoPE cos/sin tables [2048][64] ============
__global__ __launch_bounds__(256) void k_rope_tab(float* __restrict__ cosT,
                                                  float* __restrict__ sinT,
                                                  const int* __restrict__ hdim,
                                                  const int* __restrict__ wdim) {
  int idx = blockIdx.x * 256 + threadIdx.x;
  if (idx >= 2048 * 64) return;
  const int n = idx >> 6, j = idx & 63;
  const int H = *hdim, W = *wdim;
  const int w = n % W;
  const int rem = n / W;
  const int h = rem % H;
  const int t = rem / H;
  float pos, i2, d;
  if (j < 22)      { pos = (float)t; i2 = (float)(2 * j);        d = 44.f; }
  else if (j < 43) { pos = (float)h; i2 = (float)(2 * (j - 22)); d = 42.f; }
  else             { pos = (float)w; i2 = (float)(2 * (j - 43)); d = 42.f; }
  const float ang = pos * powf(10000.0f, -i2 / d);
  cosT[idx] = cosf(ang);
  sinT[idx] = sinf(ang);
}

// ============ 3a. QKV GEMM: 128x192, BK=64, 2-phase counted-vmcnt,
// ONE barrier per phase (post-MFMA barrier removed; WAR proven by lgkmcnt-before-
// next-barrier argument). bf16 out.
__global__ __launch_bounds__(256, 2) void k_gemmQKV(const unsigned short* __restrict__ A,
                                                    const unsigned short* __restrict__ B,
                                                    const float* __restrict__ bias,
                                                    unsigned short* __restrict__ C,
                                                    int M, int N, int K) {
  __shared__ __align__(16) char lds[81920];
  const int tid = threadIdx.x;
  const int lane = tid & 63;
  const int wid = tid >> 6;
  const int wr = wid >> 1, wc = wid & 1;

  const int xcd = blockIdx.x & 7;
  const int t = blockIdx.x >> 3;
  const int bx = xcd * 4 + (t & 3);
  const int by = t >> 2;
  const int row0 = by * 128, col0 = bx * 192;
  const int NT = K >> 6;

  auto stageA = [&](int grow0, int kcol0, char* slot) {
#pragma unroll
    for (int r = 0; r < 2; ++r) {
      const int off = r * 4096 + tid * 16;
      const int pair = off >> 7;
      const int un = (off & 127) ^ ((pair & 7) << 4);
      const int grow = pair * 2 + (un >> 6);
      gload_lds16(A + (size_t)(grow0 + grow) * K + kcol0 + ((un & 63) >> 1),
                  slot + r * 4096 + wid * 1024);
    }
  };
  auto stageB = [&](int grow0, int kcol0, char* slot) {
#pragma unroll
    for (int r = 0; r < 3; ++r) {
      const int off = r * 4096 + tid * 16;
      const int pair = off >> 7;
      const int un = (off & 127) ^ ((pair & 7) << 4);
      const int grow = pair * 2 + (un >> 6);
      gload_lds16(B + (size_t)(grow0 + grow) * K + kcol0 + ((un & 63) >> 1),
                  slot + r * 4096 + wid * 1024);
    }
  };
  auto frag = [&](const char* slot, int r, int kb) -> bf16x8 {
    return *reinterpret_cast<const bf16x8*>(
        slot + (r >> 1) * 128 + ((((r & 1) << 6) + kb) ^ (((r >> 1) & 7) << 4)));
  };

  f32x4 acc[4][6];
#pragma unroll
  for (int i = 0; i < 4; ++i)
#pragma unroll
    for (int j = 0; j < 6; ++j) acc[i][j] = (f32x4){0.f, 0.f, 0.f, 0.f};

  stageA(row0, 0,  lds);
  stageB(col0, 0,  lds + 16384);
  stageA(row0, 32, lds + 8192);
  stageB(col0, 32, lds + 28672);
  asm volatile("s_waitcnt vmcnt(5)" ::: "memory");
  __builtin_amdgcn_s_barrier();

  const int kb = (lane >> 4) << 4;
  for (int j = 0; j < NT; ++j) {
    const int b = j & 1, bp = b ^ 1;
    const char* base = lds + b * 40960;
    char* pbase = lds + bp * 40960;
    const bool pf = (j + 1 < NT);
    const int kn = (j + 1) * 64;
    bf16x8 af[4], bq[6];

    // ---- ph1: ks0 ----
#pragma unroll
    for (int fr = 0; fr < 4; ++fr) af[fr] = frag(base, wr * 64 + fr * 16 + (lane & 15), kb);
#pragma unroll
    for (int fc = 0; fc < 6; ++fc) bq[fc] = frag(base + 16384, wc * 96 + fc * 16 + (lane & 15), kb);
    if (pf) { stageA(row0, kn, pbase); stageB(col0, kn, pbase + 16384); }
    if (pf) asm volatile("s_waitcnt vmcnt(5)" ::: "memory");
    else    asm volatile("s_waitcnt vmcnt(0)" ::: "memory");
    __builtin_amdgcn_s_barrier();
    __builtin_amdgcn_s_setprio(1);
#pragma unroll
    for (int fr = 0; fr < 4; ++fr)
#pragma unroll
      for (int fc = 0; fc < 6; ++fc)
        acc[fr][fc] = __builtin_amdgcn_mfma_f32_16x16x32_bf16(af[fr], bq[fc], acc[fr][fc], 0, 0, 0);
    __builtin_amdgcn_s_setprio(0);

    // ---- ph2: ks1 ----
#pragma unroll
    for (int fr = 0; fr < 4; ++fr) af[fr] = frag(base + 8192, wr * 64 + fr * 16 + (lane & 15), kb);
#pragma unroll
    for (int fc = 0; fc < 6; ++fc) bq[fc] = frag(base + 28672, wc * 96 + fc * 16 + (lane & 15), kb);
    if (pf) { stageA(row0, kn + 32, pbase + 8192); stageB(col0, kn + 32, pbase + 28672); }
    if (pf) asm volatile("s_waitcnt vmcnt(5)" ::: "memory");
    __builtin_amdgcn_s_barrier();
    __builtin_amdgcn_s_setprio(1);
#pragma unroll
    for (int fr = 0; fr < 4; ++fr)
#pragma unroll
      for (int fc = 0; fc < 6; ++fc)
        acc[fr][fc] = __builtin_amdgcn_mfma_f32_16x16x32_bf16(af[fr], bq[fc], acc[fr][fc], 0, 0, 0);
    __builtin_amdgcn_s_setprio(0);
  }

#pragma unroll
  for (int fr = 0; fr < 4; ++fr)
#pragma unroll
    for (int fc = 0; fc < 6; ++fc) {
      const int col = col0 + wc * 96 + fc * 16 + (lane & 15);
      const float bv = bias[col];
#pragma unroll
      for (int jj = 0; jj < 4; ++jj) {
        const int row = row0 + wr * 64 + fr * 16 + (lane >> 4) * 4 + jj;
        C[(size_t)row * N + col] = f2bf(acc[fr][fc][jj] + bv);
      }
    }
}

// ============ 3b. proj GEMM: 128x128, BK=64, split-K x2, same pipelined structure,
// f32 partials (no bias). Grid (16,16,2) = 512 blocks, LDS 64KB -> 2/CU.
__global__ __launch_bounds__(256, 2) void k_gemmProj(const unsigned short* __restrict__ A,
                                                     const unsigned short* __restrict__ B,
                                                     float* __restrict__ Cp,
                                                     int M, int N, int K, int KS) {
  __shared__ __align__(16) char lds[65536];   // 2 bufs x (A0 8K | A1 8K | B0 8K | B1 8K)
  const int tid = threadIdx.x;
  const int lane = tid & 63;
  const int wid = tid >> 6;
  const int wr = wid >> 1, wc = wid & 1;
  const int row0 = blockIdx.y * 128;
  const int col0 = blockIdx.x * 128;
  const int k0 = blockIdx.z * KS;
  const int NT = KS >> 6;

  auto stageS = [&](const unsigned short* src, int grow0, int kcol0, char* slot) {
#pragma unroll
    for (int r = 0; r < 2; ++r) {
      const int off = r * 4096 + tid * 16;
      const int pair = off >> 7;
      const int un = (off & 127) ^ ((pair & 7) << 4);
      const int grow = pair * 2 + (un >> 6);
      gload_lds16(src + (size_t)(grow0 + grow) * K + kcol0 + ((un & 63) >> 1),
                  slot + r * 4096 + wid * 1024);
    }
  };
  auto frag = [&](const char* slot, int r, int kb) -> bf16x8 {
    return *reinterpret_cast<const bf16x8*>(
        slot + (r >> 1) * 128 + ((((r & 1) << 6) + kb) ^ (((r >> 1) & 7) << 4)));
  };

  f32x4 acc[4][4];
#pragma unroll
  for (int i = 0; i < 4; ++i)
#pragma unroll
    for (int j = 0; j < 4; ++j) acc[i][j] = (f32x4){0.f, 0.f, 0.f, 0.f};

  // buf layout: A0 @0, A1 @8K, B0 @16K, B1 @24K; bufs at 0 / 32K.
  stageS(A, row0, k0,      lds);
  stageS(B, col0, k0,      lds + 16384);
  stageS(A, row0, k0 + 32, lds + 8192);
  stageS(B, col0, k0 + 32, lds + 24576);
  asm volatile("s_waitcnt vmcnt(4)" ::: "memory");
  __builtin_amdgcn_s_barrier();

  const int kb = (lane >> 4) << 4;
  for (int j = 0; j < NT; ++j) {
    const int b = j & 1, bp = b ^ 1;
    const char* base = lds + b * 32768;
    char* pbase = lds + bp * 32768;
    const bool pf = (j + 1 < NT);
    const int kn = k0 + (j + 1) * 64;
    bf16x8 af[4], bq[4];

    // ---- ph1: ks0 ----
#pragma unroll
    for (int fr = 0; fr < 4; ++fr) af[fr] = frag(base, wr * 64 + fr * 16 + (lane & 15), kb);
#pragma unroll
    for (int fc = 0; fc < 4; ++fc) bq[fc] = frag(base + 16384, wc * 64 + fc * 16 + (lane & 15), kb);
    if (pf) { stageS(A, row0, kn, pbase); stageS(B, col0, kn, pbase + 16384); }
    if (pf) asm volatile("s_waitcnt vmcnt(4)" ::: "memory");
    else    asm volatile("s_waitcnt vmcnt(0)" ::: "memory");
    __builtin_amdgcn_s_barrier();
    __builtin_amdgcn_s_setprio(1);
#pragma unroll
    for (int fr = 0; fr < 4; ++fr)
#pragma unroll
      for (int fc = 0; fc < 4; ++fc)
        acc[fr][fc] = __builtin_amdgcn_mfma_f32_16x16x32_bf16(af[fr], bq[fc], acc[fr][fc], 0, 0, 0);
    __builtin_amdgcn_s_setprio(0);

    // ---- ph2: ks1 ----
#pragma unroll
    for (int fr = 0; fr < 4; ++fr) af[fr] = frag(base + 8192, wr * 64 + fr * 16 + (lane & 15), kb);
#pragma unroll
    for (int fc = 0; fc < 4; ++fc) bq[fc] = frag(base + 24576, wc * 64 + fc * 16 + (lane & 15), kb);
    if (pf) { stageS(A, row0, kn + 32, pbase + 8192); stageS(B, col0, kn + 32, pbase + 24576); }
    if (pf) asm volatile("s_waitcnt vmcnt(4)" ::: "memory");
    __builtin_amdgcn_s_barrier();
    __builtin_amdgcn_s_setprio(1);
#pragma unroll
    for (int fr = 0; fr < 4; ++fr)
#pragma unroll
      for (int fc = 0; fc < 4; ++fc)
        acc[fr][fc] = __builtin_amdgcn_mfma_f32_16x16x32_bf16(af[fr], bq[fc], acc[fr][fc], 0, 0, 0);
    __builtin_amdgcn_s_setprio(0);
  }

  float* Cz = Cp + (size_t)blockIdx.z * M * N;
#pragma unroll
  for (int fr = 0; fr < 4; ++fr)
#pragma unroll
    for (int fc = 0; fc < 4; ++fc) {
      const int col = col0 + wc * 64 + fc * 16 + (lane & 15);
#pragma unroll
      for (int jj = 0; jj < 4; ++jj) {
        const int row = row0 + wr * 64 + fr * 16 + (lane >> 4) * 4 + jj;
        Cz[(size_t)row * N + col] = acc[fr][fc][jj];
      }
    }
}

// ============ 3c. sum split-K partials + bias -> f32 out ============
__global__ __launch_bounds__(256) void k_addbias(const float* __restrict__ Cp,
                                                 const float* __restrict__ bias,
                                                 float* __restrict__ out) {
  const int i = blockIdx.x * 256 + threadIdx.x;
  const float4 a = reinterpret_cast<const float4*>(Cp)[i];
  const float4 b = reinterpret_cast<const float4*>(Cp + 2048ull * 2048)[i];
  const float4 bv = reinterpret_cast<const float4*>(bias)[i & 511];
  float4 o;
  o.x = a.x + b.x + bv.x; o.y = a.y + b.y + bv.y;
  o.z = a.z + b.z + bv.z; o.w = a.w + b.w + bv.w;
  reinterpret_cast<float4*>(out)[i] = o;
}

// ============ 4a. q/k: RMSNorm + RoPE + (q: fold scale) from bf16 qkv ============
__global__ __launch_bounds__(256) void k_qk_post(const unsigned short* __restrict__ qkv,
                                                 const float* __restrict__ qw,
                                                 const float* __restrict__ kw,
                                                 const float* __restrict__ cosT,
                                                 const float* __restrict__ sinT,
                                                 unsigned short* __restrict__ qo,
                                                 unsigned short* __restrict__ ko) {
  const int lane = threadIdx.x & 63;
  const int wid = threadIdx.x >> 6;
  const int pair = blockIdx.x * 4 + wid;
  const int n = pair >> 4, h = pair & 15;
  const float c = cosT[n * 64 + lane];
  const float s = sinT[n * 64 + lane];
#pragma unroll
  for (int sq = 0; sq < 2; ++sq) {
    const unsigned short* src = qkv + (size_t)n * 6144 + sq * 2048 + h * 128;
    const unsigned int vp = reinterpret_cast<const unsigned int*>(src)[lane];
    const float vx = bf2f((unsigned short)(vp & 0xffff));
    const float vy = bf2f((unsigned short)(vp >> 16));
    float ss = vx * vx + vy * vy;
#pragma unroll
    for (int m = 1; m < 64; m <<= 1) ss += __shfl_xor(ss, m, 64);
    const float r = rsqrtf(ss * (1.0f / 128.0f) + 1e-6f);
    float2 wv = reinterpret_cast<const float2*>(sq == 0 ? qw : kw)[lane];
    const float xr = vx * r * wv.x;
    const float xi = vy * r * wv.y;
    float orr = xr * c - xi * s;
    float oi  = xr * s + xi * c;
    if (sq == 0) { orr *= 0.08838834764831845f; oi *= 0.08838834764831845f; }
    unsigned short* dst = (sq == 0 ? qo : ko) + ((size_t)h * 2048 + n) * 128 + 2 * lane;
    const unsigned int pk = (unsigned int)f2bf(orr) | ((unsigned int)f2bf(oi) << 16);
    *reinterpret_cast<unsigned int*>(dst) = pk;
  }
}

// ============ 4b. v: bf16 qkv -> vt2, MFMA-fragment-ordered (lane-direct) ====
__global__ __launch_bounds__(256) void k_v_tr(const unsigned short* __restrict__ qkv,
                                              unsigned short* __restrict__ vt2) {
  __shared__ __align__(16) unsigned short tile[64][136];
  const int h = blockIdx.y;
  const int n0 = blockIdx.x * 64;
  const int t = threadIdx.x;
  {
    const int row = t >> 2;
    const int c0 = (t & 3) * 32;
    const unsigned short* src = qkv + (size_t)(n0 + row) * 6144 + 4096 + h * 128 + c0;
#pragma unroll
    for (int j = 0; j < 32; j += 8)
      *reinterpret_cast<bf16x8*>(&tile[row][c0 + j]) =
          *reinterpret_cast<const bf16x8*>(src + j);
  }
  __syncthreads();
#pragma unroll
  for (int g4 = 0; g4 < 4; ++g4) {
    const int g = g4 * 256 + t;
    const int c = g >> 8;
    const int dblk = (g >> 6) & 3;
    const int p = g & 63;
    const int d = dblk * 32 + (p & 31);
    const int hi = p >> 5;
    bf16x8 o;
#pragma unroll
    for (int e = 0; e < 8; ++e) o[e] = (short)tile[c * 16 + hi * 8 + e][d];
    const size_t oidx = ((((size_t)h * 128 + (n0 >> 4) + c) * 4 + dblk) * 64 + p) * 8;
    *reinterpret_cast<bf16x8*>(vt2 + oidx) = o;
  }
}

// ============ 5. flash attention v7b (unchanged from R13) ============
__global__ __launch_bounds__(256) void k_fattn(const unsigned short* __restrict__ q,
                                               const unsigned short* __restrict__ k,
                                               const unsigned short* __restrict__ vt2,
                                               unsigned short* __restrict__ Onorm,
                                               float* __restrict__ lseb) {
  __shared__ __align__(16) unsigned short Ks[2][64 * 128];
  __shared__ __align__(16) unsigned short Vs[2][64 * 128];
  const int lane = threadIdx.x & 63;
  const int wid = threadIdx.x >> 6;
  const int hi2 = lane >> 5;
  const int ql = lane & 31;
  const int bid = blockIdx.x;
  const int h = bid & 15;
  const int qb = (bid >> 4) & 15;
  const int ksp = bid >> 8;
  const int q0 = qb * 128 + wid * 32;
  const int kbase = ksp * 1024;

  auto stageK = [&](int buf, int kt2) {
#pragma unroll
    for (int r = 0; r < 4; ++r) {
      const int off = r * 4096 + (wid * 64 + lane) * 16;
      const int row = off >> 8;
      const int colb = (off & 255) ^ ((row & 15) << 4);
      gload_lds16(k + ((size_t)h * 2048 + kbase + kt2 * 64 + row) * 128 + (colb >> 1),
                  (char*)Ks[buf] + r * 4096 + wid * 1024);
    }
  };
  auto stageV = [&](int buf, int kt2) {
    const unsigned short* vbase = vt2 + ((size_t)h * 128 + (kbase >> 4) + kt2 * 4) * 2048;
#pragma unroll
    for (int r = 0; r < 4; ++r)
      gload_lds16(vbase + r * 2048 + (wid * 64 + lane) * 8,
                  (char*)Vs[buf] + r * 4096 + wid * 1024);
  };

  bf16x8 qf[8];
  {
    const unsigned short* qp = q + ((size_t)h * 2048 + q0 + ql) * 128 + hi2 * 8;
#pragma unroll
    for (int c = 0; c < 8; ++c) qf[c] = *reinterpret_cast<const bf16x8*>(qp + c * 16);
  }
  f32x16 O[4];
#pragma unroll
  for (int i = 0; i < 4; ++i)
#pragma unroll
    for (int j = 0; j < 16; ++j) O[i][j] = 0.f;
  float m = -1e30f, l = 0.f;

  stageK(0, 0);
  stageV(0, 0);
  asm volatile("s_waitcnt vmcnt(0)" ::: "memory");
  __builtin_amdgcn_s_barrier();

  const int kswz = (lane & 15) << 4;
  for (int kt = 0; kt < 16; ++kt) {
    const int cur = kt & 1;
    const bool pf = (kt + 1 < 16);
    if (pf) { stageK(cur ^ 1, kt + 1); stageV(cur ^ 1, kt + 1); }

    f32x16 s0, s1;
#pragma unroll
    for (int j = 0; j < 16; ++j) { s0[j] = 0.f; s1[j] = 0.f; }
    __builtin_amdgcn_s_setprio(1);
#pragma unroll
    for (int c = 0; c < 8; ++c) {
      bf16x8 a0 = *reinterpret_cast<const bf16x8*>(
          (const char*)Ks[cur] + ql * 256 + ((c * 32 + hi2 * 16) ^ kswz));
      s0 = __builtin_amdgcn_mfma_f32_32x32x16_bf16(a0, qf[c], s0, 0, 0, 0);
    }
#pragma unroll
    for (int c = 0; c < 8; ++c) {
      bf16x8 a1 = *reinterpret_cast<const bf16x8*>(
          (const char*)Ks[cur] + (32 + ql) * 256 + ((c * 32 + hi2 * 16) ^ kswz));
      s1 = __builtin_amdgcn_mfma_f32_32x32x16_bf16(a1, qf[c], s1, 0, 0, 0);
    }
    __builtin_amdgcn_s_setprio(0);

    float mt = s0[0];
#pragma unroll
    for (int j = 1; j < 16; ++j) mt = fmaxf(mt, s0[j]);
#pragma unroll
    for (int j = 0; j < 16; ++j) mt = fmaxf(mt, s1[j]);
    mt = fmaxf(mt, __shfl_xor(mt, 32, 64));

    if (!__all(mt <= m + 8.0f)) {
      const float mn = fmaxf(m, mt);
      const float al = __expf(m - mn);
      m = mn;
      l *= al;
#pragma unroll
      for (int i = 0; i < 4; ++i)
#pragma unroll
        for (int j = 0; j < 16; ++j) O[i][j] *= al;
    }
    float rs = 0.f;
#pragma unroll
    for (int j = 0; j < 16; ++j) {
      s0[j] = __expf(s0[j] - m); rs += s0[j];
      s1[j] = __expf(s1[j] - m); rs += s1[j];
    }
    rs += __shfl_xor(rs, 32, 64);
    l += rs;

    bf16x8 pfr[4];
#pragma unroll
    for (int half = 0; half < 2; ++half) {
      const f32x16& sv = half ? s1 : s0;
      unsigned a[8];
#pragma unroll
      for (int j2 = 0; j2 < 8; ++j2) a[j2] = cvtpk(sv[2 * j2], sv[2 * j2 + 1]);
      pswap(a[0], a[2]);
      pswap(a[1], a[3]);
      pswap(a[4], a[6]);
      pswap(a[5], a[7]);
      union { uint4 u; bf16x8 v; } p0, p1;
      p0.u.x = a[0]; p0.u.y = a[1]; p0.u.z = a[2]; p0.u.w = a[3];
      p1.u.x = a[4]; p1.u.y = a[5]; p1.u.z = a[6]; p1.u.w = a[7];
      pfr[half * 2 + 0] = p0.v;
      pfr[half * 2 + 1] = p1.v;
    }

    __builtin_amdgcn_s_setprio(1);
#pragma unroll
    for (int dblk = 0; dblk < 4; ++dblk) {
#pragma unroll
      for (int c2 = 0; c2 < 4; ++c2) {
        bf16x8 va = *reinterpret_cast<const bf16x8*>(
            (const char*)Vs[cur] + ((c2 * 4 + dblk) * 64 + lane) * 16);
        O[dblk] = __builtin_amdgcn_mfma_f32_32x32x16_bf16(va, pfr[c2], O[dblk], 0, 0, 0);
      }
    }
    __builtin_amdgcn_s_setprio(0);

    if (pf) {
      asm volatile("s_waitcnt vmcnt(0)" ::: "memory");
      __builtin_amdgcn_s_barrier();
    }
  }

  const float rl = 1.0f / l;
  const int n = q0 + ql;
  unsigned short* ob = Onorm + (((size_t)(ksp * 16 + h) * 2048) + n) * 128;
#pragma unroll
  for (int dblk = 0; dblk < 4; ++dblk)
#pragma unroll
    for (int a = 0; a < 4; ++a) {
      uint2 w;
      w.x = (unsigned)f2bf(O[dblk][a * 4 + 0] * rl) | ((unsigned)f2bf(O[dblk][a * 4 + 1] * rl) << 16);
      w.y = (unsigned)f2bf(O[dblk][a * 4 + 2] * rl) | ((unsigned)f2bf(O[dblk][a * 4 + 3] * rl) << 16);
      *reinterpret_cast<uint2*>(ob + dblk * 32 + a * 8 + hi2 * 4) = w;
    }
  if (hi2 == 0)
    lseb[(size_t)(ksp * 16 + h) * 2048 + n] = m + logf(l);
}

// ============ 6. merge the two key-split partials ============
__global__ __launch_bounds__(256) void k_merge(const unsigned short* __restrict__ Onorm,
                                               const float* __restrict__ lseb,
                                               unsigned short* __restrict__ att) {
  const int idx = blockIdx.x * 256 + threadIdx.x;
  const int n = idx >> 8;
  const int r = idx & 255;
  const int h = r >> 4;
  const int d0 = (r & 15) * 8;
  const float l0 = lseb[(size_t)h * 2048 + n];
  const float l1 = lseb[(size_t)(16 + h) * 2048 + n];
  const float M = fmaxf(l0, l1);
  float w0 = __expf(l0 - M), w1 = __expf(l1 - M);
  const float inv = 1.0f / (w0 + w1);
  w0 *= inv; w1 *= inv;
  const bf16x8 o0 = *reinterpret_cast<const bf16x8*>(
      Onorm + ((size_t)h * 2048 + n) * 128 + d0);
  const bf16x8 o1 = *reinterpret_cast<const bf16x8*>(
      Onorm + ((size_t)(16 + h) * 2048 + n) * 128 + d0);
  bf16x8 o;
#pragma unroll
  for (int e = 0; e < 8; ++e)
    o[e] = (short)f2bf(bf2f((unsigned short)o0[e]) * w0 + bf2f((unsigned short)o1[e]) * w1);
  *reinterpret_cast<bf16x8*>(att + (size_t)n * 2048 + h * 128 + d0) = o;
}

extern "C" void kernel_launch(void* const* d_in, const int* in_sizes, int n_in,
                              void* d_out, int out_size, void* d_ws, size_t ws_size,
                              hipStream_t stream) {
  (void)in_sizes; (void)n_in; (void)out_size; (void)ws_size;
  const float* x      = (const float*)d_in[0];
  const float* qkv_w  = (const float*)d_in[1];
  const float* qkv_b  = (const float*)d_in[2];
  const float* proj_w = (const float*)d_in[3];
  const float* proj_b = (const float*)d_in[4];
  const float* q_nw   = (const float*)d_in[5];
  const float* k_nw   = (const float*)d_in[6];
  const int* h_dim    = (const int*)d_in[8];
  const int* w_dim    = (const int*)d_in[9];
  float* out = (float*)d_out;

  char* ws = (char*)d_ws;
  size_t off = 0;
  auto carve = [&](size_t bytes) -> void* {
    void* p = ws + off;
    off += (bytes + 255) & ~(size_t)255;
    return p;
  };
  unsigned short* x_bf   = (unsigned short*)carve(2048ull * 2048 * 2);
  unsigned short* w1_bf  = (unsigned short*)carve(6144ull * 2048 * 2);
  unsigned short* w2_bf  = (unsigned short*)carve(2048ull * 2048 * 2);
  unsigned short* qkvb   = (unsigned short*)carve(2048ull * 6144 * 2);
  unsigned short* q_bf   = (unsigned short*)carve(16ull * 2048 * 128 * 2);
  unsigned short* k_bf   = (unsigned short*)carve(16ull * 2048 * 128 * 2);
  unsigned short* vt2_bf = (unsigned short*)carve(16ull * 2048 * 128 * 2);
  unsigned short* att_bf = (unsigned short*)carve(2048ull * 2048 * 2);
  unsigned short* on_bf  = (unsigned short*)carve(2ull * 16 * 2048 * 128 * 2);
  float*          lseb   = (float*)carve(2ull * 16 * 2048 * 4);
  float*          projp  = (float*)carve(2ull * 2048 * 2048 * 4);
  float*          cosT   = (float*)carve(2048ull * 64 * 4);
  float*          sinT   = (float*)carve(2048ull * 64 * 4);

  hipLaunchKernelGGL(k_cvt_bf16, dim3(2048), dim3(256), 0, stream, x, x_bf, 2048 * 2048 / 4);
  hipLaunchKernelGGL(k_cvt_bf16, dim3(2048), dim3(256), 0, stream, qkv_w, w1_bf, 6144 * 2048 / 4);
  hipLaunchKernelGGL(k_cvt_bf16, dim3(2048), dim3(256), 0, stream, proj_w, w2_bf, 2048 * 2048 / 4);
  hipLaunchKernelGGL(k_rope_tab, dim3(512), dim3(256), 0, stream, cosT, sinT, h_dim, w_dim);
  hipLaunchKernelGGL(k_gemmQKV, dim3(512), dim3(256), 0, stream,
                     x_bf, w1_bf, qkv_b, qkvb, 2048, 6144, 2048);
  hipLaunchKernelGGL(k_qk_post, dim3(8192), dim3(256), 0, stream,
                     qkvb, q_nw, k_nw, cosT, sinT, q_bf, k_bf);
  hipLaunchKernelGGL(k_v_tr, dim3(32, 16), dim3(256), 0, stream, qkvb, vt2_bf);
  hipLaunchKernelGGL(k_fattn, dim3(512), dim3(256), 0, stream,
                     q_bf, k_bf, vt2_bf, on_bf, lseb);
  hipLaunchKernelGGL(k_merge, dim3(2048), dim3(256), 0, stream, on_bf, lseb, att_bf);
  hipLaunchKernelGGL(k_gemmProj, dim3(16, 16, 2), dim3(256), 0, stream,
                     att_bf, w2_bf, projp, 2048, 2048, 2048, 1024);
  hipLaunchKernelGGL(k_addbias, dim3(4096), dim3(256), 0, stream, projp, proj_b, out);
}